// Round 7
// baseline (503.094 us; speedup 1.0000x reference)
//
#include <hip/hip_runtime.h>

#define NU 100000
#define NI 100000
#define NE 1600000
#define BB 16384
#define DD 128

static constexpr int SCAN_CHUNK = 2048;                       // 256 threads * 8
static constexpr int SCAN_NBLK  = (NU + SCAN_CHUNK - 1) / SCAN_CHUNK; // 49
static constexpr int USER_TILES = NU / 16;                    // 6250

static constexpr int NXCD   = 8;
static constexpr int DRANGE = NU / NXCD;                      // 12500 dsts per range
static constexpr int K_CH   = 32;                             // edge chunks
static constexpr int CHUNK4 = NE / 4 / K_CH;                  // 12500 int4 per chunk
static constexpr int HIST_BLKS = NXCD * K_CH;                 // 256
static constexpr int PACK_BLKS = 48;
static constexpr int CVT_UNIT  = 2048;                        // uint2 outputs per block
static constexpr int CVT_TOT   = NU * 32;                     // 3.2M uint2 (= NU*64 uints)
static constexpr int CVT_BLKS  = (CVT_TOT + CVT_UNIT - 1) / CVT_UNIT; // 1563

// ---------- workspace layout (bytes) ----------
static constexpr size_t OFF_DEG      = 0;          // int[NU]   400000
static constexpr size_t OFF_ROWSTART = 400128;     // int[NU]
static constexpr size_t OFF_BSUM     = 1200384;    // int[64]
static constexpr size_t OFF_EDGESRC  = 1200640;    // int[NE]   6400000
static constexpr size_t OFF_H1       = 7600640;    // float[NU*DD] 51200000
static constexpr size_t OFF_WFRAG    = 58800640;   // u32x4[12288] 196608 (pre-swizzled bf16 weights)

// d_out staging (dead before real outputs are written):
//   ubf  at d_out+0          : uint[NU*64]   25.6 MB (ufeat bf16 pairs; dead after l1_fuse)
//   hist at d_out+51.2MB     : int[8*32*12500] 12.8 MB (chunk histograms / cursor bases;
//                              dead after fill2)

typedef __bf16 bf16x8 __attribute__((ext_vector_type(8)));
typedef float f32x4 __attribute__((ext_vector_type(4)));
typedef unsigned int u32x4 __attribute__((ext_vector_type(4)));

union frag_u {
    u32x4 u;
    bf16x8 b;
    unsigned short us[8];
};

// ---------- helpers ----------
__device__ __forceinline__ unsigned short f2bf(float f) {
    unsigned u = __float_as_uint(f);
    u = (u + 0x7fffu + ((u >> 16) & 1u)) >> 16;  // RNE
    return (unsigned short)u;
}

__device__ __forceinline__ unsigned pack_bf16_pair(float a, float b) {
    return (unsigned)f2bf(a) | ((unsigned)f2bf(b) << 16);
}

__device__ __forceinline__ float2 unpack_bf16_pair(unsigned u) {
    float2 r;
    r.x = __uint_as_float(u << 16);
    r.y = __uint_as_float(u & 0xffff0000u);
    return r;
}

__device__ __forceinline__ f32x4 mfma16(bf16x8 a, bf16x8 b, f32x4 c) {
    return __builtin_amdgcn_mfma_f32_16x16x32_bf16(a, b, c, 0, 0, 0);
}

__device__ __forceinline__ bf16x8 bfrag(const u32x4* __restrict__ wf, int idx) {
    frag_u f;
    f.u = wf[idx];
    return f.b;
}

// A-fragment (16x16x32 layout: lane holds A[m=lane&15][kb..kb+7]) as hi/lo bf16 split.
__device__ __forceinline__ void make_afrag_hilo(const float* rowp, int kb,
                                                bf16x8* hi, bf16x8* lo) {
    float4 v0 = *(const float4*)(rowp + kb);
    float4 v1 = *(const float4*)(rowp + kb + 4);
    float vv[8] = {v0.x, v0.y, v0.z, v0.w, v1.x, v1.y, v1.z, v1.w};
    frag_u h, l;
    #pragma unroll
    for (int e = 0; e < 8; ++e) {
        unsigned short hb = f2bf(vv[e]);
        h.us[e] = hb;
        float hf = __uint_as_float(((unsigned)hb) << 16);
        l.us[e] = f2bf(vv[e] - hf);
    }
    *hi = h.b;
    *lo = l.b;
}

// ---------- mega prep: LDS histograms + weight pack + ufeat cvt ----------
__global__ __launch_bounds__(256) void mega_prep(
    const int* __restrict__ dst, int* __restrict__ hist,
    const float* __restrict__ uf, unsigned* __restrict__ ubf,
    const float* __restrict__ Ws0, const float* __restrict__ Wn0,
    const float* __restrict__ Ws1, const float* __restrict__ Wn1,
    const float* __restrict__ Wi0, const float* __restrict__ Wi1,
    u32x4* __restrict__ wfrag) {
    __shared__ int h[DRANGE];  // 50 KB
    int t = threadIdx.x;
    if (blockIdx.x < HIST_BLKS) {
        int r = blockIdx.x & (NXCD - 1);
        int k = blockIdx.x >> 3;
        for (int j = t; j < DRANGE; j += 256) h[j] = 0;
        __syncthreads();
        int lo = r * DRANGE;
        const int4* d4 = (const int4*)dst + (size_t)k * CHUNK4;
        for (int i = t; i < CHUNK4; i += 256) {
            int4 d = d4[i];
            if ((unsigned)(d.x - lo) < (unsigned)DRANGE) atomicAdd(&h[d.x - lo], 1);
            if ((unsigned)(d.y - lo) < (unsigned)DRANGE) atomicAdd(&h[d.y - lo], 1);
            if ((unsigned)(d.z - lo) < (unsigned)DRANGE) atomicAdd(&h[d.z - lo], 1);
            if ((unsigned)(d.w - lo) < (unsigned)DRANGE) atomicAdd(&h[d.w - lo], 1);
        }
        __syncthreads();
        int* hb = hist + (size_t)(r * K_CH + k) * DRANGE;
        for (int j = t; j < DRANGE; j += 256) hb[j] = h[j];
    } else if (blockIdx.x < HIST_BLKS + PACK_BLKS) {
        int i = (blockIdx.x - HIST_BLKS) * 256 + t;  // 12288 exact
        const float* tab[6] = {Ws0, Wn0, Ws1, Wn1, Wi0, Wi1};
        int matg = i >> 11;
        int j = (i >> 8) & 7, kk = (i >> 6) & 3, ln = i & 63;
        const float* W = tab[matg];
        int n = j * 16 + (ln & 15);
        int kb = kk * 32 + (ln >> 4) * 8;
        unsigned short u[8];
        #pragma unroll
        for (int e = 0; e < 8; ++e) u[e] = f2bf(W[(size_t)(kb + e) * DD + n]);
        u32x4 w;
        w[0] = u[0] | ((unsigned)u[1] << 16);
        w[1] = u[2] | ((unsigned)u[3] << 16);
        w[2] = u[4] | ((unsigned)u[5] << 16);
        w[3] = u[6] | ((unsigned)u[7] << 16);
        wfrag[i] = w;
    } else {
        int bid2 = blockIdx.x - HIST_BLKS - PACK_BLKS;
        const float4* uf4 = (const float4*)uf;
        uint2* ub2 = (uint2*)ubf;
        #pragma unroll
        for (int it = 0; it < 8; ++it) {
            int idx = bid2 * CVT_UNIT + it * 256 + t;
            if (idx < CVT_TOT) {
                float4 v = uf4[idx];
                uint2 o;
                o.x = pack_bf16_pair(v.x, v.y);
                o.y = pack_bf16_pair(v.z, v.w);
                ub2[idx] = o;
            }
        }
    }
}

// ---------- scan1 (fused deg_reduce): deg[d] = sum_k hist, block sums ----------
__global__ __launch_bounds__(256) void scan1_kernel(const int* __restrict__ hist,
                                                    int* __restrict__ deg,
                                                    int* __restrict__ bsum) {
    __shared__ int sh[256];
    int t = threadIdx.x;
    int base = blockIdx.x * SCAN_CHUNK + t * 8;
    int s = 0;
    #pragma unroll
    for (int j = 0; j < 8; ++j) {
        int idx = base + j;
        if (idx < NU) {
            int r = idx / DRANGE, jj = idx - r * DRANGE;
            const int* hb = hist + (size_t)r * K_CH * DRANGE + jj;
            int d = 0;
            #pragma unroll
            for (int k = 0; k < K_CH; ++k) d += hb[(size_t)k * DRANGE];
            deg[idx] = d;
            s += d;
        }
    }
    sh[t] = s;
    __syncthreads();
    for (int off = 128; off > 0; off >>= 1) {
        if (t < off) sh[t] += sh[t + off];
        __syncthreads();
    }
    if (t == 0) bsum[blockIdx.x] = sh[0];
}

__global__ void scan2_kernel(int* __restrict__ bsum) {
    if (threadIdx.x == 0) {
        int acc = 0;
        for (int i = 0; i < SCAN_NBLK; ++i) {
            int v = bsum[i];
            bsum[i] = acc;
            acc += v;
        }
    }
}

// ---------- scan3 (fused base): row_start + hist -> per-(r,k) cursor bases ------
__global__ __launch_bounds__(256) void scan3_kernel(const int* __restrict__ deg,
                                                    const int* __restrict__ bsum,
                                                    int* __restrict__ row_start,
                                                    int* __restrict__ hist) {
    __shared__ int sh[256];
    int t = threadIdx.x;
    int base = blockIdx.x * SCAN_CHUNK + t * 8;
    int v[8];
    int s = 0;
    #pragma unroll
    for (int j = 0; j < 8; ++j) {
        int idx = base + j;
        v[j] = (idx < NU) ? deg[idx] : 0;
        s += v[j];
    }
    sh[t] = s;
    __syncthreads();
    for (int off = 1; off < 256; off <<= 1) {
        int val = sh[t];
        int add = (t >= off) ? sh[t - off] : 0;
        __syncthreads();
        sh[t] = val + add;
        __syncthreads();
    }
    int excl = sh[t] - s + bsum[blockIdx.x];
    #pragma unroll
    for (int j = 0; j < 8; ++j) {
        int idx = base + j;
        if (idx < NU) {
            row_start[idx] = excl;
            // base walk: hist[r][k][jj] -> cursor base for chunk k
            int r = idx / DRANGE, jj = idx - r * DRANGE;
            int* hb = hist + (size_t)r * K_CH * DRANGE + jj;
            int acc = excl;
            #pragma unroll
            for (int k = 0; k < K_CH; ++k) {
                int c = hb[(size_t)k * DRANGE];
                hb[(size_t)k * DRANGE] = acc;
                acc += c;
            }
        }
        excl += v[j];
    }
}

// ---------- CSR fill: LDS cursors only, zero global atomics ----------
__global__ __launch_bounds__(256) void fill2(const int* __restrict__ src,
                                             const int* __restrict__ dst,
                                             const int* __restrict__ base,
                                             int* __restrict__ edge_src) {
    __shared__ int cur[DRANGE];  // 50 KB
    int r = blockIdx.x & (NXCD - 1);
    int k = blockIdx.x >> 3;
    int t = threadIdx.x;
    const int* bb = base + (size_t)(r * K_CH + k) * DRANGE;
    for (int j = t; j < DRANGE; j += 256) cur[j] = bb[j];
    __syncthreads();
    int lo = r * DRANGE;
    const int4* d4 = (const int4*)dst + (size_t)k * CHUNK4;
    const int4* s4 = (const int4*)src + (size_t)k * CHUNK4;
    for (int i = t; i < CHUNK4; i += 256) {
        int4 d = d4[i];
        int4 s = s4[i];
        if ((unsigned)(d.x - lo) < (unsigned)DRANGE) edge_src[atomicAdd(&cur[d.x - lo], 1)] = s.x;
        if ((unsigned)(d.y - lo) < (unsigned)DRANGE) edge_src[atomicAdd(&cur[d.y - lo], 1)] = s.y;
        if ((unsigned)(d.z - lo) < (unsigned)DRANGE) edge_src[atomicAdd(&cur[d.z - lo], 1)] = s.z;
        if ((unsigned)(d.w - lo) < (unsigned)DRANGE) edge_src[atomicAdd(&cur[d.w - lo], 1)] = s.w;
    }
}

// ---------- fused user layer 1: aggregation + MFMA + l2norm -> h1 ----------
// One 16-row tile per block. Phase 1: wave w aggregates rows 4w..4w+3 from ubf
// (16 lanelets x 4 eslots, uint4 loads) into LDS fp32. Phase 2: all 4 waves
// j-split the MFMA (self hi/lo from ufeat + neighbor bf16-RNE from LDS —
// numerically identical to the old hn path), cross-wave norm, write h1.
// Eliminates the hn 25.6MB write + 25.6MB read round-trip of the old
// agg_kernel/user_mm_mfma pair and overlaps MFMA/streaming with gather latency.
__global__ __launch_bounds__(256) void l1_fuse(
    const unsigned* __restrict__ ubf, const float* __restrict__ ufeat,
    const int* __restrict__ row_start, const int* __restrict__ deg,
    const int* __restrict__ edge_src, const u32x4* __restrict__ wf,
    const float* __restrict__ bias, float* __restrict__ h1) {
    __shared__ float sc[16 * 132];   // neighbor means (fp32)
    __shared__ float ssp[16 * 4];    // per-row per-wave partial sum-of-squares
    int t = threadIdx.x;
    int lane = t & 63, wave = t >> 6;
    int gb = blockIdx.x * 16;        // 6250 blocks exact
    int lanelet = lane & 15;         // covers uints [lanelet*4 .. +3] = dims 8*lanelet..+7
    int eslot = lane >> 4;           // 4 concurrent edges
    const unsigned* colp = ubf + (lanelet << 2);
    // phase 1
    #pragma unroll
    for (int rr = 0; rr < 4; ++rr) {
        int r = wave * 4 + rr;
        int g = gb + r;
        int st = row_start[g], dg = deg[g];
        float acc[8] = {0.f, 0.f, 0.f, 0.f, 0.f, 0.f, 0.f, 0.f};
        for (int base = 0; base < dg; base += 64) {
            int n = min(dg - base, 64);
            int myidx = (lane < n) ? edge_src[st + base + lane] : 0;
            int e = 0;
            #pragma unroll 2
            for (; e + 4 <= n; e += 4) {
                int s = __shfl(myidx, e + eslot, 64);
                u32x4 v = *(const u32x4*)(colp + (size_t)s * 64);
                #pragma unroll
                for (int k = 0; k < 4; ++k) {
                    float2 f = unpack_bf16_pair(v[k]);
                    acc[2 * k] += f.x;
                    acc[2 * k + 1] += f.y;
                }
            }
            int rem = n - e;
            int s = __shfl(myidx, min(e + eslot, 63), 64);  // all lanes active
            if (eslot < rem) {
                u32x4 v = *(const u32x4*)(colp + (size_t)s * 64);
                #pragma unroll
                for (int k = 0; k < 4; ++k) {
                    float2 f = unpack_bf16_pair(v[k]);
                    acc[2 * k] += f.x;
                    acc[2 * k + 1] += f.y;
                }
            }
        }
        #pragma unroll
        for (int k = 0; k < 8; ++k) {
            acc[k] += __shfl_xor(acc[k], 16, 64);
            acc[k] += __shfl_xor(acc[k], 32, 64);
        }
        float inv = 1.0f / fmaxf((float)dg, 1.0f);
        if (eslot == 0) {
            float4 o0 = {acc[0] * inv, acc[1] * inv, acc[2] * inv, acc[3] * inv};
            float4 o1 = {acc[4] * inv, acc[5] * inv, acc[6] * inv, acc[7] * inv};
            *(float4*)(sc + r * 132 + (lanelet << 3)) = o0;
            *(float4*)(sc + r * 132 + (lanelet << 3) + 4) = o1;
        }
    }
    __syncthreads();
    // phase 2: all 4 waves, wave w computes j = 2w, 2w+1
    int m = lane & 15, q = lane >> 4;
    int j0 = wave * 2;
    const float* selfp = ufeat + (size_t)(gb + m) * DD;
    bf16x8 sh_[4], sl_[4], nb[4];
    #pragma unroll
    for (int kk = 0; kk < 4; ++kk) {
        int kb = kk * 32 + q * 8;
        make_afrag_hilo(selfp, kb, &sh_[kk], &sl_[kk]);
        const float* np = sc + m * 132 + kb;
        frag_u nf;
        #pragma unroll
        for (int e = 0; e < 8; ++e) nf.us[e] = f2bf(np[e]);  // RNE, same as old hn
        nb[kk] = nf.b;
    }
    f32x4 zero = {0.f, 0.f, 0.f, 0.f};
    f32x4 a0 = zero, a1 = zero;
    #pragma unroll
    for (int kk = 0; kk < 4; ++kk) {
        bf16x8 b0 = bfrag(wf, (j0 * 4 + kk) * 64 + lane);
        a0 = mfma16(sh_[kk], b0, a0);
        a0 = mfma16(sl_[kk], b0, a0);
        bf16x8 n0 = bfrag(wf, 2048 + (j0 * 4 + kk) * 64 + lane);
        a0 = mfma16(nb[kk], n0, a0);
        bf16x8 b1 = bfrag(wf, ((j0 + 1) * 4 + kk) * 64 + lane);
        a1 = mfma16(sh_[kk], b1, a1);
        a1 = mfma16(sl_[kk], b1, a1);
        bf16x8 n1 = bfrag(wf, 2048 + ((j0 + 1) * 4 + kk) * 64 + lane);
        a1 = mfma16(nb[kk], n1, a1);
    }
    float bj0 = bias[j0 * 16 + m], bj1 = bias[(j0 + 1) * 16 + m];
    float ss[4];
    #pragma unroll
    for (int r = 0; r < 4; ++r) {
        float x0 = a0[r] + bj0; x0 = x0 > 0.f ? x0 : 0.2f * x0; a0[r] = x0;
        float x1 = a1[r] + bj1; x1 = x1 > 0.f ? x1 : 0.2f * x1; a1[r] = x1;
        float s = x0 * x0 + x1 * x1;
        s += __shfl_xor(s, 1, 64);
        s += __shfl_xor(s, 2, 64);
        s += __shfl_xor(s, 4, 64);
        s += __shfl_xor(s, 8, 64);
        ss[r] = s;
    }
    if (m == 0) {
        #pragma unroll
        for (int r = 0; r < 4; ++r) ssp[(q * 4 + r) * 4 + wave] = ss[r];
    }
    __syncthreads();
    #pragma unroll
    for (int r = 0; r < 4; ++r) {
        int row = q * 4 + r;
        float tot = ssp[row * 4] + ssp[row * 4 + 1] + ssp[row * 4 + 2] + ssp[row * 4 + 3];
        float inv = 1.0f / fmaxf(sqrtf(tot), 1e-12f);
        h1[(size_t)(gb + row) * DD + j0 * 16 + m] = a0[r] * inv;
        h1[(size_t)(gb + row) * DD + (j0 + 1) * 16 + m] = a1[r] * inv;
    }
}

// ---------- fused tail: user_l2 (blocks 0..1023) + item (blocks 1024..3071) ----
__global__ __launch_bounds__(256) void tail_fuse(
    const float* __restrict__ ufeat, const float* __restrict__ h1,
    const int* __restrict__ users, const int* __restrict__ row_start,
    const int* __restrict__ deg, const int* __restrict__ edge_src,
    const float* __restrict__ ifeat, const int* __restrict__ pos,
    const int* __restrict__ neg, const u32x4* __restrict__ wf_u,
    const u32x4* __restrict__ wf_i, const float* __restrict__ bu1,
    const float* __restrict__ bi0, const float* __restrict__ bi1,
    float* __restrict__ out) {
    __shared__ float sc[16 * 132];   // 8448 B tile scratch
    __shared__ float ssp[16 * 4];    // per-row per-wave partial sum-of-squares
    int t = threadIdx.x;
    int lane = t & 63, wave = t >> 6;
    int m = lane & 15, q = lane >> 4;
    f32x4 zero = {0.f, 0.f, 0.f, 0.f};

    if (blockIdx.x < 1024) {
        // ================= user layer 2 =================
        int gb = blockIdx.x * 16;
        int L = lane & 31;      // 16B lanelet of the row
        int eslot = lane >> 5;  // 2 concurrent edges
        const float* hl = h1 + 4 * L;
        #pragma unroll
        for (int rr = 0; rr < 4; ++rr) {
            int r = wave * 4 + rr;
            int u = users[gb + r];
            int st = row_start[u], dg = deg[u];
            float ax = 0.f, ay = 0.f, az = 0.f, aw = 0.f;
            for (int base = 0; base < dg; base += 64) {
                int n = min(dg - base, 64);
                int myidx = (lane < n) ? edge_src[st + base + lane] : 0;
                int e = 0;
                #pragma unroll 4
                for (; e + 2 <= n; e += 2) {
                    int s = __shfl(myidx, e + eslot, 64);
                    float4 v = *(const float4*)(hl + (size_t)s * DD);
                    ax += v.x; ay += v.y; az += v.z; aw += v.w;
                }
                if (e < n) {
                    int s = __shfl(myidx, e, 64);
                    if (eslot == 0) {
                        float4 v = *(const float4*)(hl + (size_t)s * DD);
                        ax += v.x; ay += v.y; az += v.z; aw += v.w;
                    }
                }
            }
            ax += __shfl_xor(ax, 32, 64);
            ay += __shfl_xor(ay, 32, 64);
            az += __shfl_xor(az, 32, 64);
            aw += __shfl_xor(aw, 32, 64);
            float inv = 1.0f / fmaxf((float)dg, 1.0f);
            if (eslot == 0) {
                float4 o = {ax * inv, ay * inv, az * inv, aw * inv};
                *(float4*)(sc + r * 132 + 4 * L) = o;
            }
            float* orow = out + (size_t)(gb + r) * 384;
            ((float2*)orow)[lane] = ((const float2*)(ufeat + (size_t)u * DD))[lane];
            ((float2*)orow)[64 + lane] = ((const float2*)(h1 + (size_t)u * DD))[lane];
        }
        __syncthreads();
        // phase 2: all 4 waves; wave w computes j = 2w, 2w+1
        int j0 = wave * 2;
        int um = users[gb + m];
        const float* selfp = h1 + (size_t)um * DD;
        bf16x8 sh[4], sl[4], nh[4], nl[4];
        #pragma unroll
        for (int kk = 0; kk < 4; ++kk) {
            int kb = kk * 32 + q * 8;
            make_afrag_hilo(selfp, kb, &sh[kk], &sl[kk]);
            make_afrag_hilo(sc + m * 132, kb, &nh[kk], &nl[kk]);
        }
        f32x4 a0 = zero, a1 = zero;
        #pragma unroll
        for (int kk = 0; kk < 4; ++kk) {
            bf16x8 b0 = bfrag(wf_u, (j0 * 4 + kk) * 64 + lane);
            a0 = mfma16(sh[kk], b0, a0);
            a0 = mfma16(sl[kk], b0, a0);
            bf16x8 n0 = bfrag(wf_u, 2048 + (j0 * 4 + kk) * 64 + lane);
            a0 = mfma16(nh[kk], n0, a0);
            a0 = mfma16(nl[kk], n0, a0);
            bf16x8 b1 = bfrag(wf_u, ((j0 + 1) * 4 + kk) * 64 + lane);
            a1 = mfma16(sh[kk], b1, a1);
            a1 = mfma16(sl[kk], b1, a1);
            bf16x8 n1 = bfrag(wf_u, 2048 + ((j0 + 1) * 4 + kk) * 64 + lane);
            a1 = mfma16(nh[kk], n1, a1);
            a1 = mfma16(nl[kk], n1, a1);
        }
        float bj0 = bu1[j0 * 16 + m], bj1 = bu1[(j0 + 1) * 16 + m];
        float ss[4];
        #pragma unroll
        for (int r = 0; r < 4; ++r) {
            float x0 = a0[r] + bj0; x0 = x0 > 0.f ? x0 : 0.2f * x0; a0[r] = x0;
            float x1 = a1[r] + bj1; x1 = x1 > 0.f ? x1 : 0.2f * x1; a1[r] = x1;
            float s = x0 * x0 + x1 * x1;
            s += __shfl_xor(s, 1, 64);
            s += __shfl_xor(s, 2, 64);
            s += __shfl_xor(s, 4, 64);
            s += __shfl_xor(s, 8, 64);
            ss[r] = s;
        }
        if (m == 0) {
            #pragma unroll
            for (int r = 0; r < 4; ++r) ssp[(q * 4 + r) * 4 + wave] = ss[r];
        }
        __syncthreads();
        #pragma unroll
        for (int r = 0; r < 4; ++r) {
            int row = q * 4 + r;
            float tot = ssp[row * 4] + ssp[row * 4 + 1] + ssp[row * 4 + 2] + ssp[row * 4 + 3];
            float inv = 1.0f / fmaxf(sqrtf(tot), 1e-12f);
            out[(size_t)(gb + row) * 384 + 256 + j0 * 16 + m] = a0[r] * inv;
            out[(size_t)(gb + row) * 384 + 256 + (j0 + 1) * 16 + m] = a1[r] * inv;
        }
        return;
    }

    // ================= item side: one tile per block, j split across waves =====
    int tile = blockIdx.x - 1024;  // 2048 tiles
    int gb = tile * 16;
    int j0 = wave * 2;
    int rowm = gb + m;
    int idxm = (rowm < BB) ? pos[rowm] : neg[rowm - BB];
    const float* rowp = ifeat + (size_t)idxm * DD;
    bf16x8 ahi[4], alo[4];
    #pragma unroll
    for (int kk = 0; kk < 4; ++kk)
        make_afrag_hilo(rowp, kk * 32 + q * 8, &ahi[kk], &alo[kk]);
    f32x4 a0 = zero, a1 = zero;
    #pragma unroll
    for (int kk = 0; kk < 4; ++kk) {
        bf16x8 b0 = bfrag(wf_i, (j0 * 4 + kk) * 64 + lane);
        a0 = mfma16(ahi[kk], b0, a0);
        a0 = mfma16(alo[kk], b0, a0);
        bf16x8 b1 = bfrag(wf_i, ((j0 + 1) * 4 + kk) * 64 + lane);
        a1 = mfma16(ahi[kk], b1, a1);
        a1 = mfma16(alo[kk], b1, a1);
    }
    // epilogue 0: cross-wave norm, write r1 to scratch
    {
        float bj0 = bi0[j0 * 16 + m], bj1 = bi0[(j0 + 1) * 16 + m];
        float ss[4];
        #pragma unroll
        for (int r = 0; r < 4; ++r) {
            float x0 = a0[r] + bj0; x0 = x0 > 0.f ? x0 : 0.2f * x0; a0[r] = x0;
            float x1 = a1[r] + bj1; x1 = x1 > 0.f ? x1 : 0.2f * x1; a1[r] = x1;
            float s = x0 * x0 + x1 * x1;
            s += __shfl_xor(s, 1, 64);
            s += __shfl_xor(s, 2, 64);
            s += __shfl_xor(s, 4, 64);
            s += __shfl_xor(s, 8, 64);
            ss[r] = s;
        }
        if (m == 0) {
            #pragma unroll
            for (int r = 0; r < 4; ++r) ssp[(q * 4 + r) * 4 + wave] = ss[r];
        }
        __syncthreads();
        #pragma unroll
        for (int r = 0; r < 4; ++r) {
            int row = q * 4 + r;
            float tot = ssp[row * 4] + ssp[row * 4 + 1] + ssp[row * 4 + 2] + ssp[row * 4 + 3];
            float inv = 1.0f / fmaxf(sqrtf(tot), 1e-12f);
            sc[row * 132 + j0 * 16 + m] = a0[r] * inv;
            sc[row * 132 + (j0 + 1) * 16 + m] = a1[r] * inv;
        }
        __syncthreads();
    }
    // copy r0 (raw gathered ifeat) and r1 (from scratch): rows split across waves
    #pragma unroll
    for (int rr = 0; rr < 4; ++rr) {
        int r = wave * 4 + rr;
        int row = gb + r;
        int idx = (row < BB) ? pos[row] : neg[row - BB];
        float* orow = out + (size_t)(BB + row) * 384;
        ((float2*)orow)[lane] = ((const float2*)(ifeat + (size_t)idx * DD))[lane];
        float2 r1v;
        r1v.x = sc[r * 132 + 2 * lane];
        r1v.y = sc[r * 132 + 2 * lane + 1];
        ((float2*)orow)[64 + lane] = r1v;
    }
    // layer 1: A-frags from scratch
    bf16x8 chi[4], clo[4];
    #pragma unroll
    for (int kk = 0; kk < 4; ++kk)
        make_afrag_hilo(sc + m * 132, kk * 32 + q * 8, &chi[kk], &clo[kk]);
    a0 = zero; a1 = zero;
    #pragma unroll
    for (int kk = 0; kk < 4; ++kk) {
        bf16x8 b0 = bfrag(wf_i, 2048 + (j0 * 4 + kk) * 64 + lane);
        a0 = mfma16(chi[kk], b0, a0);
        a0 = mfma16(clo[kk], b0, a0);
        bf16x8 b1 = bfrag(wf_i, 2048 + ((j0 + 1) * 4 + kk) * 64 + lane);
        a1 = mfma16(chi[kk], b1, a1);
        a1 = mfma16(clo[kk], b1, a1);
    }
    {
        float bj0 = bi1[j0 * 16 + m], bj1 = bi1[(j0 + 1) * 16 + m];
        float ss[4];
        #pragma unroll
        for (int r = 0; r < 4; ++r) {
            float x0 = a0[r] + bj0; x0 = x0 > 0.f ? x0 : 0.2f * x0; a0[r] = x0;
            float x1 = a1[r] + bj1; x1 = x1 > 0.f ? x1 : 0.2f * x1; a1[r] = x1;
            float s = x0 * x0 + x1 * x1;
            s += __shfl_xor(s, 1, 64);
            s += __shfl_xor(s, 2, 64);
            s += __shfl_xor(s, 4, 64);
            s += __shfl_xor(s, 8, 64);
            ss[r] = s;
        }
        __syncthreads();  // ensure prior ssp reads done before rewrite
        if (m == 0) {
            #pragma unroll
            for (int r = 0; r < 4; ++r) ssp[(q * 4 + r) * 4 + wave] = ss[r];
        }
        __syncthreads();
        #pragma unroll
        for (int r = 0; r < 4; ++r) {
            int row = q * 4 + r;
            float tot = ssp[row * 4] + ssp[row * 4 + 1] + ssp[row * 4 + 2] + ssp[row * 4 + 3];
            float inv = 1.0f / fmaxf(sqrtf(tot), 1e-12f);
            out[(size_t)(BB + gb + row) * 384 + 256 + j0 * 16 + m] = a0[r] * inv;
            out[(size_t)(BB + gb + row) * 384 + 256 + (j0 + 1) * 16 + m] = a1[r] * inv;
        }
    }
}

extern "C" void kernel_launch(void* const* d_in, const int* in_sizes, int n_in,
                              void* d_out, int out_size, void* d_ws, size_t ws_size,
                              hipStream_t stream) {
    const int* src = (const int*)d_in[0];
    const int* dst = (const int*)d_in[1];
    const int* users = (const int*)d_in[2];
    const int* pos = (const int*)d_in[3];
    const int* neg = (const int*)d_in[4];
    const float* ufeat = (const float*)d_in[5];
    const float* ifeat = (const float*)d_in[6];
    const float* Ws0 = (const float*)d_in[7];
    const float* Wn0 = (const float*)d_in[8];
    const float* bu0 = (const float*)d_in[9];
    const float* Wi0 = (const float*)d_in[10];
    const float* bi0 = (const float*)d_in[11];
    const float* Ws1 = (const float*)d_in[12];
    const float* Wn1 = (const float*)d_in[13];
    const float* bu1 = (const float*)d_in[14];
    const float* Wi1 = (const float*)d_in[15];
    const float* bi1 = (const float*)d_in[16];
    float* out = (float*)d_out;

    char* ws = (char*)d_ws;
    int* deg = (int*)(ws + OFF_DEG);
    int* row_start = (int*)(ws + OFF_ROWSTART);
    int* bsum = (int*)(ws + OFF_BSUM);
    int* edge_src = (int*)(ws + OFF_EDGESRC);
    float* h1 = (float*)(ws + OFF_H1);
    u32x4* wfrag = (u32x4*)(ws + OFF_WFRAG);

    unsigned* ubf = (unsigned*)d_out;                                    // bf16 ufeat
    int* hist = (int*)((char*)d_out + (size_t)NU * DD * 4);              // 12.8MB at +51.2MB

    mega_prep<<<HIST_BLKS + PACK_BLKS + CVT_BLKS, 256, 0, stream>>>(
        dst, hist, ufeat, ubf, Ws0, Wn0, Ws1, Wn1, Wi0, Wi1, wfrag);
    scan1_kernel<<<SCAN_NBLK, 256, 0, stream>>>(hist, deg, bsum);
    scan2_kernel<<<1, 64, 0, stream>>>(bsum);
    scan3_kernel<<<SCAN_NBLK, 256, 0, stream>>>(deg, bsum, row_start, hist);
    fill2<<<HIST_BLKS, 256, 0, stream>>>(src, dst, hist, edge_src);
    l1_fuse<<<USER_TILES, 256, 0, stream>>>(ubf, ufeat, row_start, deg, edge_src,
                                            wfrag, bu0, h1);
    tail_fuse<<<1024 + 2048, 256, 0, stream>>>(ufeat, h1, users, row_start, deg, edge_src,
                                               ifeat, pos, neg, wfrag + 4096, wfrag + 8192,
                                               bu1, bi0, bi1, out);
}

// Round 8
// 486.311 us; speedup vs baseline: 1.0345x; 1.0345x over previous
//
#include <hip/hip_runtime.h>

#define NU 100000
#define NI 100000
#define NE 1600000
#define BB 16384
#define DD 128

static constexpr int SCAN_CHUNK = 2048;                       // 256 threads * 8
static constexpr int SCAN_NBLK  = (NU + SCAN_CHUNK - 1) / SCAN_CHUNK; // 49
static constexpr int USER_TILES = NU / 16;                    // 6250

static constexpr int NXCD   = 8;
static constexpr int DRANGE = NU / NXCD;                      // 12500 dsts per range
static constexpr int K_CH   = 32;                             // edge chunks
static constexpr int CHUNK4 = NE / 4 / K_CH;                  // 12500 int4 per chunk
static constexpr int HIST_BLKS = NXCD * K_CH;                 // 256
static constexpr int PACK_BLKS = 48;
static constexpr int UBF_ROWS  = 98304;                       // ubf rows staged in d_out[0,25.17MB)
static constexpr int CVT_UNIT  = 2048;                        // uint2 outputs per block
static constexpr int CVT_TOT   = UBF_ROWS * 32;               // 3,145,728 uint2
static constexpr int CVT_BLKS  = CVT_TOT / CVT_UNIT;          // 1536 exact

static constexpr int NITEM  = 2048;                           // item tiles
static constexpr int AGG_BLKS = NU / 4;                       // 25000
static constexpr int AI_BLKS  = AGG_BLKS + NITEM;             // 27048

// ---------- workspace layout (bytes) ----------
static constexpr size_t OFF_DEG      = 0;          // int[NU]   400000
static constexpr size_t OFF_ROWSTART = 400128;     // int[NU]
static constexpr size_t OFF_BSUM     = 1200384;    // int[64]
static constexpr size_t OFF_EDGESRC  = 1200640;    // int[NE]   6400000
static constexpr size_t OFF_H1       = 7600640;    // float[NU*DD] 51200000
static constexpr size_t OFF_WFRAG    = 58800640;   // u32x4[12288] 196608 (pre-swizzled bf16 weights)

// d_out staging (dead before the real outputs land):
//   ubf  at d_out[0, 25,165,824)  : uint[UBF_ROWS*64] — bf16 ufeat rows 0..98303,
//        exactly the user-out region (written by tail_user AFTER agg consumed ubf).
//        Rows >= 98304 are gathered from fp32 ufeat directly (1.7% of edges).
//   hist at d_out+51.2MB : int[8*32*12500] 12.8 MB — dead after fill2; item blocks
//        (running inside agg_item_fuse, after fill2) may overwrite freely.
//   hn lives interleaved in ws h1 slots: row g's bf16 mean = first 256 B of h1's
//        512 B row-g slot. agg writes it; user_mm's wave for tile g reads it and
//        then overwrites the slot with h1 (same-wave load->mfma->store order).

typedef __bf16 bf16x8 __attribute__((ext_vector_type(8)));
typedef float f32x4 __attribute__((ext_vector_type(4)));
typedef unsigned int u32x4 __attribute__((ext_vector_type(4)));

union frag_u {
    u32x4 u;
    bf16x8 b;
    unsigned short us[8];
};

// ---------- helpers ----------
__device__ __forceinline__ unsigned short f2bf(float f) {
    unsigned u = __float_as_uint(f);
    u = (u + 0x7fffu + ((u >> 16) & 1u)) >> 16;  // RNE
    return (unsigned short)u;
}

__device__ __forceinline__ unsigned pack_bf16_pair(float a, float b) {
    return (unsigned)f2bf(a) | ((unsigned)f2bf(b) << 16);
}

__device__ __forceinline__ float2 unpack_bf16_pair(unsigned u) {
    float2 r;
    r.x = __uint_as_float(u << 16);
    r.y = __uint_as_float(u & 0xffff0000u);
    return r;
}

__device__ __forceinline__ f32x4 mfma16(bf16x8 a, bf16x8 b, f32x4 c) {
    return __builtin_amdgcn_mfma_f32_16x16x32_bf16(a, b, c, 0, 0, 0);
}

__device__ __forceinline__ bf16x8 bfrag(const u32x4* __restrict__ wf, int idx) {
    frag_u f;
    f.u = wf[idx];
    return f.b;
}

// A-fragment (16x16x32 layout: lane holds A[m=lane&15][kb..kb+7]) as hi/lo bf16 split.
__device__ __forceinline__ void make_afrag_hilo(const float* rowp, int kb,
                                                bf16x8* hi, bf16x8* lo) {
    float4 v0 = *(const float4*)(rowp + kb);
    float4 v1 = *(const float4*)(rowp + kb + 4);
    float vv[8] = {v0.x, v0.y, v0.z, v0.w, v1.x, v1.y, v1.z, v1.w};
    frag_u h, l;
    #pragma unroll
    for (int e = 0; e < 8; ++e) {
        unsigned short hb = f2bf(vv[e]);
        h.us[e] = hb;
        float hf = __uint_as_float(((unsigned)hb) << 16);
        l.us[e] = f2bf(vv[e] - hf);
    }
    *hi = h.b;
    *lo = l.b;
}

// ---------- mega prep: LDS histograms + weight pack + ufeat cvt ----------
__global__ __launch_bounds__(256) void mega_prep(
    const int* __restrict__ dst, int* __restrict__ hist,
    const float* __restrict__ uf, unsigned* __restrict__ ubf,
    const float* __restrict__ Ws0, const float* __restrict__ Wn0,
    const float* __restrict__ Ws1, const float* __restrict__ Wn1,
    const float* __restrict__ Wi0, const float* __restrict__ Wi1,
    u32x4* __restrict__ wfrag) {
    __shared__ int h[DRANGE];  // 50 KB
    int t = threadIdx.x;
    if (blockIdx.x < HIST_BLKS) {
        int r = blockIdx.x & (NXCD - 1);
        int k = blockIdx.x >> 3;
        for (int j = t; j < DRANGE; j += 256) h[j] = 0;
        __syncthreads();
        int lo = r * DRANGE;
        const int4* d4 = (const int4*)dst + (size_t)k * CHUNK4;
        for (int i = t; i < CHUNK4; i += 256) {
            int4 d = d4[i];
            if ((unsigned)(d.x - lo) < (unsigned)DRANGE) atomicAdd(&h[d.x - lo], 1);
            if ((unsigned)(d.y - lo) < (unsigned)DRANGE) atomicAdd(&h[d.y - lo], 1);
            if ((unsigned)(d.z - lo) < (unsigned)DRANGE) atomicAdd(&h[d.z - lo], 1);
            if ((unsigned)(d.w - lo) < (unsigned)DRANGE) atomicAdd(&h[d.w - lo], 1);
        }
        __syncthreads();
        int* hb = hist + (size_t)(r * K_CH + k) * DRANGE;
        for (int j = t; j < DRANGE; j += 256) hb[j] = h[j];
    } else if (blockIdx.x < HIST_BLKS + PACK_BLKS) {
        int i = (blockIdx.x - HIST_BLKS) * 256 + t;  // 12288 exact
        const float* tab[6] = {Ws0, Wn0, Ws1, Wn1, Wi0, Wi1};
        int matg = i >> 11;
        int j = (i >> 8) & 7, kk = (i >> 6) & 3, ln = i & 63;
        const float* W = tab[matg];
        int n = j * 16 + (ln & 15);
        int kb = kk * 32 + (ln >> 4) * 8;
        unsigned short u[8];
        #pragma unroll
        for (int e = 0; e < 8; ++e) u[e] = f2bf(W[(size_t)(kb + e) * DD + n]);
        u32x4 w;
        w[0] = u[0] | ((unsigned)u[1] << 16);
        w[1] = u[2] | ((unsigned)u[3] << 16);
        w[2] = u[4] | ((unsigned)u[5] << 16);
        w[3] = u[6] | ((unsigned)u[7] << 16);
        wfrag[i] = w;
    } else {
        int bid2 = blockIdx.x - HIST_BLKS - PACK_BLKS;
        const float4* uf4 = (const float4*)uf;
        uint2* ub2 = (uint2*)ubf;
        #pragma unroll
        for (int it = 0; it < 8; ++it) {
            int idx = bid2 * CVT_UNIT + it * 256 + t;  // CVT_TOT exact multiple
            float4 v = uf4[idx];
            uint2 o;
            o.x = pack_bf16_pair(v.x, v.y);
            o.y = pack_bf16_pair(v.z, v.w);
            ub2[idx] = o;
        }
    }
}

// ---------- deg[d] = sum_k hist[r][k][j] (thread-per-element, coalesced) -------
__global__ __launch_bounds__(256) void deg_reduce(const int* __restrict__ hist,
                                                  int* __restrict__ deg) {
    int d = blockIdx.x * 256 + threadIdx.x;
    if (d >= NU) return;
    int r = d / DRANGE, j = d - r * DRANGE;
    const int* hb = hist + (size_t)r * K_CH * DRANGE + j;
    int s = 0;
    #pragma unroll
    for (int k = 0; k < K_CH; ++k) s += hb[(size_t)k * DRANGE];
    deg[d] = s;
}

__global__ __launch_bounds__(256) void scan1_kernel(const int* __restrict__ deg,
                                                    int* __restrict__ bsum) {
    __shared__ int sh[256];
    int t = threadIdx.x;
    int base = blockIdx.x * SCAN_CHUNK + t * 8;
    int s = 0;
    #pragma unroll
    for (int j = 0; j < 8; ++j) {
        int idx = base + j;
        s += (idx < NU) ? deg[idx] : 0;
    }
    sh[t] = s;
    __syncthreads();
    for (int off = 128; off > 0; off >>= 1) {
        if (t < off) sh[t] += sh[t + off];
        __syncthreads();
    }
    if (t == 0) bsum[blockIdx.x] = sh[0];
}

__global__ void scan2_kernel(int* __restrict__ bsum) {
    if (threadIdx.x == 0) {
        int acc = 0;
        for (int i = 0; i < SCAN_NBLK; ++i) {
            int v = bsum[i];
            bsum[i] = acc;
            acc += v;
        }
    }
}

__global__ __launch_bounds__(256) void scan3_kernel(const int* __restrict__ deg,
                                                    const int* __restrict__ bsum,
                                                    int* __restrict__ row_start) {
    __shared__ int sh[256];
    int t = threadIdx.x;
    int base = blockIdx.x * SCAN_CHUNK + t * 8;
    int v[8];
    int s = 0;
    #pragma unroll
    for (int j = 0; j < 8; ++j) {
        int idx = base + j;
        v[j] = (idx < NU) ? deg[idx] : 0;
        s += v[j];
    }
    sh[t] = s;
    __syncthreads();
    for (int off = 1; off < 256; off <<= 1) {
        int val = sh[t];
        int add = (t >= off) ? sh[t - off] : 0;
        __syncthreads();
        sh[t] = val + add;
        __syncthreads();
    }
    int excl = sh[t] - s + bsum[blockIdx.x];
    #pragma unroll
    for (int j = 0; j < 8; ++j) {
        int idx = base + j;
        if (idx < NU) row_start[idx] = excl;
        excl += v[j];
    }
}

// ---------- hist -> per-(r,k) cursor bases (thread-per-element, coalesced) -----
__global__ __launch_bounds__(256) void base_kernel(const int* __restrict__ row_start,
                                                   int* __restrict__ hist) {
    int d = blockIdx.x * 256 + threadIdx.x;
    if (d >= NU) return;
    int r = d / DRANGE, j = d - r * DRANGE;
    int* hb = hist + (size_t)r * K_CH * DRANGE + j;
    int acc = row_start[d];
    #pragma unroll
    for (int k = 0; k < K_CH; ++k) {
        int c = hb[(size_t)k * DRANGE];
        hb[(size_t)k * DRANGE] = acc;
        acc += c;
    }
}

// ---------- CSR fill: LDS cursors only, zero global atomics ----------
__global__ __launch_bounds__(256) void fill2(const int* __restrict__ src,
                                             const int* __restrict__ dst,
                                             const int* __restrict__ base,
                                             int* __restrict__ edge_src) {
    __shared__ int cur[DRANGE];  // 50 KB
    int r = blockIdx.x & (NXCD - 1);
    int k = blockIdx.x >> 3;
    int t = threadIdx.x;
    const int* bb = base + (size_t)(r * K_CH + k) * DRANGE;
    for (int j = t; j < DRANGE; j += 256) cur[j] = bb[j];
    __syncthreads();
    int lo = r * DRANGE;
    const int4* d4 = (const int4*)dst + (size_t)k * CHUNK4;
    const int4* s4 = (const int4*)src + (size_t)k * CHUNK4;
    for (int i = t; i < CHUNK4; i += 256) {
        int4 d = d4[i];
        int4 s = s4[i];
        if ((unsigned)(d.x - lo) < (unsigned)DRANGE) edge_src[atomicAdd(&cur[d.x - lo], 1)] = s.x;
        if ((unsigned)(d.y - lo) < (unsigned)DRANGE) edge_src[atomicAdd(&cur[d.y - lo], 1)] = s.y;
        if ((unsigned)(d.z - lo) < (unsigned)DRANGE) edge_src[atomicAdd(&cur[d.z - lo], 1)] = s.z;
        if ((unsigned)(d.w - lo) < (unsigned)DRANGE) edge_src[atomicAdd(&cur[d.w - lo], 1)] = s.w;
    }
}

// ---------- agg + item fused launch ----------
// Item blocks interleaved 1-in-13 (positions 13k+6, k<2048) so their MFMA/VALU
// work fills agg's gather-latency stalls across the whole launch. Remaining
// 25000 positions are agg blocks (4 independent waves, one row each, no syncs).
// agg writes the neighbor mean (bf16 pairs) into the first 256 B of h1's row
// slot; item writes out rows BB..3BB (disjoint from ubf in d_out[0,25.17MB)).
__global__ __launch_bounds__(256) void agg_item_fuse(
    const unsigned* __restrict__ ubf, const float* __restrict__ ufeat,
    const int* __restrict__ row_start, const int* __restrict__ deg,
    const int* __restrict__ edge_src, float* __restrict__ h1,
    const float* __restrict__ ifeat, const int* __restrict__ pos,
    const int* __restrict__ neg, const u32x4* __restrict__ wf_i,
    const float* __restrict__ bi0, const float* __restrict__ bi1,
    float* __restrict__ out) {
    __shared__ float sc[16 * 132];   // item scratch
    __shared__ float ssp[16 * 4];
    int bid = blockIdx.x;
    int t = threadIdx.x;
    int lane = t & 63, wave = t >> 6;
    bool is_item = (bid % 13 == 6) && (bid / 13 < NITEM);

    if (!is_item) {
        // ================= agg: one row per wave, no barriers =================
        int agg_bid = bid - min(NITEM, (bid + 6) / 13);
        int wid = agg_bid * 4 + wave;   // < NU exact
        int st = row_start[wid];
        int dg = deg[wid];
        int lanelet = lane & 15;        // dims 8L..8L+7
        int eslot = lane >> 4;          // 4 concurrent edges
        float acc[8] = {0.f, 0.f, 0.f, 0.f, 0.f, 0.f, 0.f, 0.f};
        const unsigned* colp = ubf + (lanelet << 2);
        const float* fcol = ufeat + (lanelet << 3);
        for (int base = 0; base < dg; base += 64) {
            int n = min(dg - base, 64);
            int myidx = (lane < n) ? edge_src[st + base + lane] : 0;
            int e = 0;
            #pragma unroll 2
            for (; e + 4 <= n; e += 4) {
                int s = __shfl(myidx, e + eslot, 64);
                if (s < UBF_ROWS) {
                    u32x4 v = *(const u32x4*)(colp + (size_t)s * 64);
                    #pragma unroll
                    for (int k = 0; k < 4; ++k) {
                        float2 f = unpack_bf16_pair(v[k]);
                        acc[2 * k] += f.x;
                        acc[2 * k + 1] += f.y;
                    }
                } else {  // 1.7% of edges: fp32 gather (ubf tail not staged)
                    const float* fp = fcol + (size_t)s * DD;
                    float4 a = *(const float4*)fp;
                    float4 b = *(const float4*)(fp + 4);
                    acc[0] += a.x; acc[1] += a.y; acc[2] += a.z; acc[3] += a.w;
                    acc[4] += b.x; acc[5] += b.y; acc[6] += b.z; acc[7] += b.w;
                }
            }
            int rem = n - e;
            int s = __shfl(myidx, min(e + eslot, 63), 64);  // all lanes active
            if (eslot < rem) {
                if (s < UBF_ROWS) {
                    u32x4 v = *(const u32x4*)(colp + (size_t)s * 64);
                    #pragma unroll
                    for (int k = 0; k < 4; ++k) {
                        float2 f = unpack_bf16_pair(v[k]);
                        acc[2 * k] += f.x;
                        acc[2 * k + 1] += f.y;
                    }
                } else {
                    const float* fp = fcol + (size_t)s * DD;
                    float4 a = *(const float4*)fp;
                    float4 b = *(const float4*)(fp + 4);
                    acc[0] += a.x; acc[1] += a.y; acc[2] += a.z; acc[3] += a.w;
                    acc[4] += b.x; acc[5] += b.y; acc[6] += b.z; acc[7] += b.w;
                }
            }
        }
        #pragma unroll
        for (int k = 0; k < 8; ++k) {
            acc[k] += __shfl_xor(acc[k], 16, 64);
            acc[k] += __shfl_xor(acc[k], 32, 64);
        }
        float inv = 1.0f / fmaxf((float)dg, 1.0f);
        if (eslot == 0) {
            u32x4 o;
            o[0] = pack_bf16_pair(acc[0] * inv, acc[1] * inv);
            o[1] = pack_bf16_pair(acc[2] * inv, acc[3] * inv);
            o[2] = pack_bf16_pair(acc[4] * inv, acc[5] * inv);
            o[3] = pack_bf16_pair(acc[6] * inv, acc[7] * inv);
            // hn row wid -> first 256 B of h1's 512 B slot
            unsigned* hnu = (unsigned*)h1;
            *(u32x4*)(hnu + (size_t)wid * 128 + (lanelet << 2)) = o;
        }
        return;
    }

    // ================= item tile: j split across waves =================
    int tile = bid / 13;
    int gb = tile * 16;
    int m = lane & 15, q = lane >> 4;
    int j0 = wave * 2;
    f32x4 zero = {0.f, 0.f, 0.f, 0.f};
    int rowm = gb + m;
    int idxm = (rowm < BB) ? pos[rowm] : neg[rowm - BB];
    const float* rowp = ifeat + (size_t)idxm * DD;
    bf16x8 ahi[4], alo[4];
    #pragma unroll
    for (int kk = 0; kk < 4; ++kk)
        make_afrag_hilo(rowp, kk * 32 + q * 8, &ahi[kk], &alo[kk]);
    f32x4 a0 = zero, a1 = zero;
    #pragma unroll
    for (int kk = 0; kk < 4; ++kk) {
        bf16x8 b0 = bfrag(wf_i, (j0 * 4 + kk) * 64 + lane);
        a0 = mfma16(ahi[kk], b0, a0);
        a0 = mfma16(alo[kk], b0, a0);
        bf16x8 b1 = bfrag(wf_i, ((j0 + 1) * 4 + kk) * 64 + lane);
        a1 = mfma16(ahi[kk], b1, a1);
        a1 = mfma16(alo[kk], b1, a1);
    }
    // epilogue 0: cross-wave norm, write r1 to scratch
    {
        float bj0 = bi0[j0 * 16 + m], bj1 = bi0[(j0 + 1) * 16 + m];
        float ss[4];
        #pragma unroll
        for (int r = 0; r < 4; ++r) {
            float x0 = a0[r] + bj0; x0 = x0 > 0.f ? x0 : 0.2f * x0; a0[r] = x0;
            float x1 = a1[r] + bj1; x1 = x1 > 0.f ? x1 : 0.2f * x1; a1[r] = x1;
            float s = x0 * x0 + x1 * x1;
            s += __shfl_xor(s, 1, 64);
            s += __shfl_xor(s, 2, 64);
            s += __shfl_xor(s, 4, 64);
            s += __shfl_xor(s, 8, 64);
            ss[r] = s;
        }
        if (m == 0) {
            #pragma unroll
            for (int r = 0; r < 4; ++r) ssp[(q * 4 + r) * 4 + wave] = ss[r];
        }
        __syncthreads();
        #pragma unroll
        for (int r = 0; r < 4; ++r) {
            int row = q * 4 + r;
            float tot = ssp[row * 4] + ssp[row * 4 + 1] + ssp[row * 4 + 2] + ssp[row * 4 + 3];
            float inv = 1.0f / fmaxf(sqrtf(tot), 1e-12f);
            sc[row * 132 + j0 * 16 + m] = a0[r] * inv;
            sc[row * 132 + (j0 + 1) * 16 + m] = a1[r] * inv;
        }
        __syncthreads();
    }
    // copy r0 (raw gathered ifeat) and r1 (from scratch): rows split across waves
    #pragma unroll
    for (int rr = 0; rr < 4; ++rr) {
        int r = wave * 4 + rr;
        int row = gb + r;
        int idx = (row < BB) ? pos[row] : neg[row - BB];
        float* orow = out + (size_t)(BB + row) * 384;
        ((float2*)orow)[lane] = ((const float2*)(ifeat + (size_t)idx * DD))[lane];
        float2 r1v;
        r1v.x = sc[r * 132 + 2 * lane];
        r1v.y = sc[r * 132 + 2 * lane + 1];
        ((float2*)orow)[64 + lane] = r1v;
    }
    // layer 1: A-frags from scratch
    bf16x8 chi[4], clo[4];
    #pragma unroll
    for (int kk = 0; kk < 4; ++kk)
        make_afrag_hilo(sc + m * 132, kk * 32 + q * 8, &chi[kk], &clo[kk]);
    a0 = zero; a1 = zero;
    #pragma unroll
    for (int kk = 0; kk < 4; ++kk) {
        bf16x8 b0 = bfrag(wf_i, 2048 + (j0 * 4 + kk) * 64 + lane);
        a0 = mfma16(chi[kk], b0, a0);
        a0 = mfma16(clo[kk], b0, a0);
        bf16x8 b1 = bfrag(wf_i, 2048 + ((j0 + 1) * 4 + kk) * 64 + lane);
        a1 = mfma16(chi[kk], b1, a1);
        a1 = mfma16(clo[kk], b1, a1);
    }
    {
        float bj0 = bi1[j0 * 16 + m], bj1 = bi1[(j0 + 1) * 16 + m];
        float ss[4];
        #pragma unroll
        for (int r = 0; r < 4; ++r) {
            float x0 = a0[r] + bj0; x0 = x0 > 0.f ? x0 : 0.2f * x0; a0[r] = x0;
            float x1 = a1[r] + bj1; x1 = x1 > 0.f ? x1 : 0.2f * x1; a1[r] = x1;
            float s = x0 * x0 + x1 * x1;
            s += __shfl_xor(s, 1, 64);
            s += __shfl_xor(s, 2, 64);
            s += __shfl_xor(s, 4, 64);
            s += __shfl_xor(s, 8, 64);
            ss[r] = s;
        }
        __syncthreads();  // prior ssp reads done before rewrite
        if (m == 0) {
            #pragma unroll
            for (int r = 0; r < 4; ++r) ssp[(q * 4 + r) * 4 + wave] = ss[r];
        }
        __syncthreads();
        #pragma unroll
        for (int r = 0; r < 4; ++r) {
            int row = q * 4 + r;
            float tot = ssp[row * 4] + ssp[row * 4 + 1] + ssp[row * 4 + 2] + ssp[row * 4 + 3];
            float inv = 1.0f / fmaxf(sqrtf(tot), 1e-12f);
            out[(size_t)(BB + gb + row) * 384 + 256 + j0 * 16 + m] = a0[r] * inv;
            out[(size_t)(BB + gb + row) * 384 + 256 + (j0 + 1) * 16 + m] = a1[r] * inv;
        }
    }
}

// ---------- user layer 1 (all rows), MFMA; hn read from h1 slots ----------
__global__ __launch_bounds__(256) void user_mm_mfma(
    const float* __restrict__ hself, float* __restrict__ h1,
    const u32x4* __restrict__ wf, const float* __restrict__ bias) {
    int t = threadIdx.x;
    int lane = t & 63;
    int tile = blockIdx.x * 4 + (t >> 6);
    if (tile >= USER_TILES) return;
    int gbase = tile * 16;
    int m = lane & 15, q = lane >> 4;
    const float* selfp = hself + (size_t)(gbase + m) * DD;
    // hn row g = first 128 ushorts of h1's 256-ushort slot
    const unsigned short* neighp = (const unsigned short*)h1 + (size_t)(gbase + m) * 256;
    bf16x8 as_hi[4], as_lo[4], an[4];
    #pragma unroll
    for (int kk = 0; kk < 4; ++kk) {
        int kb = kk * 32 + q * 8;
        make_afrag_hilo(selfp, kb, &as_hi[kk], &as_lo[kk]);
        frag_u f;
        f.u = *(const u32x4*)(neighp + kb);  // bf16 hn
        an[kk] = f.b;
    }
    f32x4 acc[8];
    f32x4 zero = {0.f, 0.f, 0.f, 0.f};
    #pragma unroll
    for (int j = 0; j < 8; ++j) acc[j] = zero;
    #pragma unroll 2
    for (int j = 0; j < 8; ++j) {
        #pragma unroll
        for (int kk = 0; kk < 4; ++kk) {
            bf16x8 bs = bfrag(wf, (j * 4 + kk) * 64 + lane);
            acc[j] = mfma16(as_hi[kk], bs, acc[j]);
            acc[j] = mfma16(as_lo[kk], bs, acc[j]);
            bf16x8 bn = bfrag(wf, 2048 + (j * 4 + kk) * 64 + lane);
            acc[j] = mfma16(an[kk], bn, acc[j]);
        }
    }
    float ss[4] = {0.f, 0.f, 0.f, 0.f};
    #pragma unroll
    for (int j = 0; j < 8; ++j) {
        float bj = bias[j * 16 + m];
        #pragma unroll
        for (int r = 0; r < 4; ++r) {
            float x = acc[j][r] + bj;
            x = x > 0.f ? x : 0.2f * x;
            acc[j][r] = x;
            ss[r] += x * x;
        }
    }
    #pragma unroll
    for (int r = 0; r < 4; ++r) {
        float s = ss[r];
        s += __shfl_xor(s, 1, 64);
        s += __shfl_xor(s, 2, 64);
        s += __shfl_xor(s, 4, 64);
        s += __shfl_xor(s, 8, 64);
        ss[r] = 1.0f / fmaxf(sqrtf(s), 1e-12f);
    }
    // stores depend on all hn loads via the MFMA chain -> same-wave RAW is safe
    #pragma unroll
    for (int j = 0; j < 8; ++j)
        #pragma unroll
        for (int r = 0; r < 4; ++r)
            h1[(size_t)(gbase + q * 4 + r) * DD + j * 16 + m] = acc[j][r] * ss[r];
}

// ---------- tail: user_l2 only (1024 blocks, one 16-row tile per block) --------
__global__ __launch_bounds__(256) void tail_user(
    const float* __restrict__ ufeat, const float* __restrict__ h1,
    const int* __restrict__ users, const int* __restrict__ row_start,
    const int* __restrict__ deg, const int* __restrict__ edge_src,
    const u32x4* __restrict__ wf_u, const float* __restrict__ bu1,
    float* __restrict__ out) {
    __shared__ float sc[16 * 132];
    __shared__ float ssp[16 * 4];
    int t = threadIdx.x;
    int lane = t & 63, wave = t >> 6;
    int m = lane & 15, q = lane >> 4;
    f32x4 zero = {0.f, 0.f, 0.f, 0.f};
    int gb = blockIdx.x * 16;
    int L = lane & 31;      // 16B lanelet of the row
    int eslot = lane >> 5;  // 2 concurrent edges
    const float* hl = h1 + 4 * L;
    #pragma unroll
    for (int rr = 0; rr < 4; ++rr) {
        int r = wave * 4 + rr;
        int u = users[gb + r];
        int st = row_start[u], dg = deg[u];
        float ax = 0.f, ay = 0.f, az = 0.f, aw = 0.f;
        for (int base = 0; base < dg; base += 64) {
            int n = min(dg - base, 64);
            int myidx = (lane < n) ? edge_src[st + base + lane] : 0;
            int e = 0;
            #pragma unroll 4
            for (; e + 2 <= n; e += 2) {
                int s = __shfl(myidx, e + eslot, 64);
                float4 v = *(const float4*)(hl + (size_t)s * DD);
                ax += v.x; ay += v.y; az += v.z; aw += v.w;
            }
            if (e < n) {
                int s = __shfl(myidx, e, 64);
                if (eslot == 0) {
                    float4 v = *(const float4*)(hl + (size_t)s * DD);
                    ax += v.x; ay += v.y; az += v.z; aw += v.w;
                }
            }
        }
        ax += __shfl_xor(ax, 32, 64);
        ay += __shfl_xor(ay, 32, 64);
        az += __shfl_xor(az, 32, 64);
        aw += __shfl_xor(aw, 32, 64);
        float inv = 1.0f / fmaxf((float)dg, 1.0f);
        if (eslot == 0) {
            float4 o = {ax * inv, ay * inv, az * inv, aw * inv};
            *(float4*)(sc + r * 132 + 4 * L) = o;
        }
        float* orow = out + (size_t)(gb + r) * 384;
        ((float2*)orow)[lane] = ((const float2*)(ufeat + (size_t)u * DD))[lane];
        ((float2*)orow)[64 + lane] = ((const float2*)(h1 + (size_t)u * DD))[lane];
    }
    __syncthreads();
    // phase 2: all 4 waves; wave w computes j = 2w, 2w+1
    int j0 = wave * 2;
    int um = users[gb + m];
    const float* selfp = h1 + (size_t)um * DD;
    bf16x8 sh[4], sl[4], nh[4], nl[4];
    #pragma unroll
    for (int kk = 0; kk < 4; ++kk) {
        int kb = kk * 32 + q * 8;
        make_afrag_hilo(selfp, kb, &sh[kk], &sl[kk]);
        make_afrag_hilo(sc + m * 132, kb, &nh[kk], &nl[kk]);
    }
    f32x4 a0 = zero, a1 = zero;
    #pragma unroll
    for (int kk = 0; kk < 4; ++kk) {
        bf16x8 b0 = bfrag(wf_u, (j0 * 4 + kk) * 64 + lane);
        a0 = mfma16(sh[kk], b0, a0);
        a0 = mfma16(sl[kk], b0, a0);
        bf16x8 n0 = bfrag(wf_u, 2048 + (j0 * 4 + kk) * 64 + lane);
        a0 = mfma16(nh[kk], n0, a0);
        a0 = mfma16(nl[kk], n0, a0);
        bf16x8 b1 = bfrag(wf_u, ((j0 + 1) * 4 + kk) * 64 + lane);
        a1 = mfma16(sh[kk], b1, a1);
        a1 = mfma16(sl[kk], b1, a1);
        bf16x8 n1 = bfrag(wf_u, 2048 + ((j0 + 1) * 4 + kk) * 64 + lane);
        a1 = mfma16(nh[kk], n1, a1);
        a1 = mfma16(nl[kk], n1, a1);
    }
    float bj0 = bu1[j0 * 16 + m], bj1 = bu1[(j0 + 1) * 16 + m];
    float ss[4];
    #pragma unroll
    for (int r = 0; r < 4; ++r) {
        float x0 = a0[r] + bj0; x0 = x0 > 0.f ? x0 : 0.2f * x0; a0[r] = x0;
        float x1 = a1[r] + bj1; x1 = x1 > 0.f ? x1 : 0.2f * x1; a1[r] = x1;
        float s = x0 * x0 + x1 * x1;
        s += __shfl_xor(s, 1, 64);
        s += __shfl_xor(s, 2, 64);
        s += __shfl_xor(s, 4, 64);
        s += __shfl_xor(s, 8, 64);
        ss[r] = s;
    }
    if (m == 0) {
        #pragma unroll
        for (int r = 0; r < 4; ++r) ssp[(q * 4 + r) * 4 + wave] = ss[r];
    }
    __syncthreads();
    #pragma unroll
    for (int r = 0; r < 4; ++r) {
        int row = q * 4 + r;
        float tot = ssp[row * 4] + ssp[row * 4 + 1] + ssp[row * 4 + 2] + ssp[row * 4 + 3];
        float inv = 1.0f / fmaxf(sqrtf(tot), 1e-12f);
        out[(size_t)(gb + row) * 384 + 256 + j0 * 16 + m] = a0[r] * inv;
        out[(size_t)(gb + row) * 384 + 256 + (j0 + 1) * 16 + m] = a1[r] * inv;
    }
}

extern "C" void kernel_launch(void* const* d_in, const int* in_sizes, int n_in,
                              void* d_out, int out_size, void* d_ws, size_t ws_size,
                              hipStream_t stream) {
    const int* src = (const int*)d_in[0];
    const int* dst = (const int*)d_in[1];
    const int* users = (const int*)d_in[2];
    const int* pos = (const int*)d_in[3];
    const int* neg = (const int*)d_in[4];
    const float* ufeat = (const float*)d_in[5];
    const float* ifeat = (const float*)d_in[6];
    const float* Ws0 = (const float*)d_in[7];
    const float* Wn0 = (const float*)d_in[8];
    const float* bu0 = (const float*)d_in[9];
    const float* Wi0 = (const float*)d_in[10];
    const float* bi0 = (const float*)d_in[11];
    const float* Ws1 = (const float*)d_in[12];
    const float* Wn1 = (const float*)d_in[13];
    const float* bu1 = (const float*)d_in[14];
    const float* Wi1 = (const float*)d_in[15];
    const float* bi1 = (const float*)d_in[16];
    float* out = (float*)d_out;

    char* ws = (char*)d_ws;
    int* deg = (int*)(ws + OFF_DEG);
    int* row_start = (int*)(ws + OFF_ROWSTART);
    int* bsum = (int*)(ws + OFF_BSUM);
    int* edge_src = (int*)(ws + OFF_EDGESRC);
    float* h1 = (float*)(ws + OFF_H1);
    u32x4* wfrag = (u32x4*)(ws + OFF_WFRAG);

    unsigned* ubf = (unsigned*)d_out;                        // rows 0..98303 only
    int* hist = (int*)((char*)d_out + (size_t)NU * DD * 4);  // 12.8MB at +51.2MB

    mega_prep<<<HIST_BLKS + PACK_BLKS + CVT_BLKS, 256, 0, stream>>>(
        dst, hist, ufeat, ubf, Ws0, Wn0, Ws1, Wn1, Wi0, Wi1, wfrag);
    deg_reduce<<<(NU + 255) / 256, 256, 0, stream>>>(hist, deg);
    scan1_kernel<<<SCAN_NBLK, 256, 0, stream>>>(deg, bsum);
    scan2_kernel<<<1, 64, 0, stream>>>(bsum);
    scan3_kernel<<<SCAN_NBLK, 256, 0, stream>>>(deg, bsum, row_start);
    base_kernel<<<(NU + 255) / 256, 256, 0, stream>>>(row_start, hist);
    fill2<<<HIST_BLKS, 256, 0, stream>>>(src, dst, hist, edge_src);
    agg_item_fuse<<<AI_BLKS, 256, 0, stream>>>(ubf, ufeat, row_start, deg, edge_src, h1,
                                               ifeat, pos, neg, wfrag + 8192, bi0, bi1, out);
    user_mm_mfma<<<(USER_TILES + 3) / 4, 256, 0, stream>>>(ufeat, h1, wfrag, bu0);
    tail_user<<<BB / 16, 256, 0, stream>>>(ufeat, h1, users, row_start, deg, edge_src,
                                           wfrag + 4096, bu1, out);
}

// Round 9
// 448.967 us; speedup vs baseline: 1.1206x; 1.0832x over previous
//
#include <hip/hip_runtime.h>

#define NU 100000
#define NI 100000
#define NE 1600000
#define BB 16384
#define DD 128

static constexpr int SCAN_CHUNK = 2048;                       // 256 threads * 8
static constexpr int SCAN_NBLK  = (NU + SCAN_CHUNK - 1) / SCAN_CHUNK; // 49
static constexpr int USER_TILES = NU / 16;                    // 6250

static constexpr int NXCD   = 8;
static constexpr int DRANGE = NU / NXCD;                      // 12500 dsts per range
static constexpr int K_CH   = 32;                             // edge chunks
static constexpr int CHUNK4 = NE / 4 / K_CH;                  // 12500 int4 per chunk
static constexpr int HIST_BLKS = NXCD * K_CH;                 // 256
static constexpr int PACK_BLKS = 48;
static constexpr int CVT_UNIT  = 2048;                        // uint2 outputs per block
static constexpr int CVT_TOT   = NU * 32;                     // 3.2M uint2 (= NU*64 uints)
static constexpr int CVT_BLKS  = (CVT_TOT + CVT_UNIT - 1) / CVT_UNIT; // 1563

// ---------- workspace layout (bytes) ----------
static constexpr size_t OFF_DEG      = 0;          // int[NU]   400000
static constexpr size_t OFF_ROWSTART = 400128;     // int[NU]
static constexpr size_t OFF_BSUM     = 1200384;    // int[64]
static constexpr size_t OFF_EDGESRC  = 1200640;    // int[NE]   6400000
static constexpr size_t OFF_H1       = 7600640;    // float[NU*DD] 51200000
static constexpr size_t OFF_WFRAG    = 58800640;   // u32x4[12288] 196608 (pre-swizzled bf16 weights)

// d_out staging (dead before real outputs are written):
//   ubf  at d_out+0          : uint[NU*64]   25.6 MB (ufeat bf16 pairs; dead after agg)
//   hn   at d_out+25.6MB     : ushort[NU*128] 25.6 MB (neighbor mean; dead after user_mm)
//   hist at d_out+51.2MB     : int[8*32*12500] 12.8 MB (chunk histograms / cursor bases;
//                              dead after fill2)

typedef __bf16 bf16x8 __attribute__((ext_vector_type(8)));
typedef float f32x4 __attribute__((ext_vector_type(4)));
typedef unsigned int u32x4 __attribute__((ext_vector_type(4)));

union frag_u {
    u32x4 u;
    bf16x8 b;
    unsigned short us[8];
};

// ---------- helpers ----------
__device__ __forceinline__ unsigned short f2bf(float f) {
    unsigned u = __float_as_uint(f);
    u = (u + 0x7fffu + ((u >> 16) & 1u)) >> 16;  // RNE
    return (unsigned short)u;
}

__device__ __forceinline__ unsigned pack_bf16_pair(float a, float b) {
    return (unsigned)f2bf(a) | ((unsigned)f2bf(b) << 16);
}

__device__ __forceinline__ float2 unpack_bf16_pair(unsigned u) {
    float2 r;
    r.x = __uint_as_float(u << 16);
    r.y = __uint_as_float(u & 0xffff0000u);
    return r;
}

__device__ __forceinline__ f32x4 mfma16(bf16x8 a, bf16x8 b, f32x4 c) {
    return __builtin_amdgcn_mfma_f32_16x16x32_bf16(a, b, c, 0, 0, 0);
}

__device__ __forceinline__ bf16x8 bfrag(const u32x4* __restrict__ wf, int idx) {
    frag_u f;
    f.u = wf[idx];
    return f.b;
}

// A-fragment (16x16x32 layout: lane holds A[m=lane&15][kb..kb+7]) as hi/lo bf16 split.
__device__ __forceinline__ void make_afrag_hilo(const float* rowp, int kb,
                                                bf16x8* hi, bf16x8* lo) {
    float4 v0 = *(const float4*)(rowp + kb);
    float4 v1 = *(const float4*)(rowp + kb + 4);
    float vv[8] = {v0.x, v0.y, v0.z, v0.w, v1.x, v1.y, v1.z, v1.w};
    frag_u h, l;
    #pragma unroll
    for (int e = 0; e < 8; ++e) {
        unsigned short hb = f2bf(vv[e]);
        h.us[e] = hb;
        float hf = __uint_as_float(((unsigned)hb) << 16);
        l.us[e] = f2bf(vv[e] - hf);
    }
    *hi = h.b;
    *lo = l.b;
}

// ---------- mega prep: LDS histograms + weight pack + ufeat cvt ----------
__global__ __launch_bounds__(256) void mega_prep(
    const int* __restrict__ dst, int* __restrict__ hist,
    const float* __restrict__ uf, unsigned* __restrict__ ubf,
    const float* __restrict__ Ws0, const float* __restrict__ Wn0,
    const float* __restrict__ Ws1, const float* __restrict__ Wn1,
    const float* __restrict__ Wi0, const float* __restrict__ Wi1,
    u32x4* __restrict__ wfrag) {
    __shared__ int h[DRANGE];  // 50 KB
    int t = threadIdx.x;
    if (blockIdx.x < HIST_BLKS) {
        int r = blockIdx.x & (NXCD - 1);
        int k = blockIdx.x >> 3;
        for (int j = t; j < DRANGE; j += 256) h[j] = 0;
        __syncthreads();
        int lo = r * DRANGE;
        const int4* d4 = (const int4*)dst + (size_t)k * CHUNK4;
        for (int i = t; i < CHUNK4; i += 256) {
            int4 d = d4[i];
            if ((unsigned)(d.x - lo) < (unsigned)DRANGE) atomicAdd(&h[d.x - lo], 1);
            if ((unsigned)(d.y - lo) < (unsigned)DRANGE) atomicAdd(&h[d.y - lo], 1);
            if ((unsigned)(d.z - lo) < (unsigned)DRANGE) atomicAdd(&h[d.z - lo], 1);
            if ((unsigned)(d.w - lo) < (unsigned)DRANGE) atomicAdd(&h[d.w - lo], 1);
        }
        __syncthreads();
        int* hb = hist + (size_t)(r * K_CH + k) * DRANGE;
        for (int j = t; j < DRANGE; j += 256) hb[j] = h[j];
    } else if (blockIdx.x < HIST_BLKS + PACK_BLKS) {
        int i = (blockIdx.x - HIST_BLKS) * 256 + t;  // 12288 exact
        const float* tab[6] = {Ws0, Wn0, Ws1, Wn1, Wi0, Wi1};
        int matg = i >> 11;
        int j = (i >> 8) & 7, kk = (i >> 6) & 3, ln = i & 63;
        const float* W = tab[matg];
        int n = j * 16 + (ln & 15);
        int kb = kk * 32 + (ln >> 4) * 8;
        unsigned short u[8];
        #pragma unroll
        for (int e = 0; e < 8; ++e) u[e] = f2bf(W[(size_t)(kb + e) * DD + n]);
        u32x4 w;
        w[0] = u[0] | ((unsigned)u[1] << 16);
        w[1] = u[2] | ((unsigned)u[3] << 16);
        w[2] = u[4] | ((unsigned)u[5] << 16);
        w[3] = u[6] | ((unsigned)u[7] << 16);
        wfrag[i] = w;
    } else {
        int bid2 = blockIdx.x - HIST_BLKS - PACK_BLKS;
        const float4* uf4 = (const float4*)uf;
        uint2* ub2 = (uint2*)ubf;
        #pragma unroll
        for (int it = 0; it < 8; ++it) {
            int idx = bid2 * CVT_UNIT + it * 256 + t;
            if (idx < CVT_TOT) {
                float4 v = uf4[idx];
                uint2 o;
                o.x = pack_bf16_pair(v.x, v.y);
                o.y = pack_bf16_pair(v.z, v.w);
                ub2[idx] = o;
            }
        }
    }
}

// ---------- scan1 (fused deg_reduce): thread-per-element coalesced ----------
// Each block covers 2048 elements in 8 strided 256-wide passes; computes
// deg[d] = sum_k hist[r][k][jj] (coalesced per k-slice) and the block sum
// (order-independent), LDS-reduced into bsum.
__global__ __launch_bounds__(256) void scan1_kernel(const int* __restrict__ hist,
                                                    int* __restrict__ deg,
                                                    int* __restrict__ bsum) {
    __shared__ int sh[256];
    int t = threadIdx.x;
    int s = 0;
    #pragma unroll
    for (int j = 0; j < 8; ++j) {
        int d = blockIdx.x * SCAN_CHUNK + j * 256 + t;
        if (d < NU) {
            int r = d / DRANGE, jj = d - r * DRANGE;
            const int* hb = hist + (size_t)r * K_CH * DRANGE + jj;
            int v = 0;
            #pragma unroll
            for (int k = 0; k < K_CH; ++k) v += hb[(size_t)k * DRANGE];
            deg[d] = v;
            s += v;
        }
    }
    sh[t] = s;
    __syncthreads();
    for (int off = 128; off > 0; off >>= 1) {
        if (t < off) sh[t] += sh[t + off];
        __syncthreads();
    }
    if (t == 0) bsum[blockIdx.x] = sh[0];
}

__global__ void scan2_kernel(int* __restrict__ bsum) {
    if (threadIdx.x == 0) {
        int acc = 0;
        for (int i = 0; i < SCAN_NBLK; ++i) {
            int v = bsum[i];
            bsum[i] = acc;
            acc += v;
        }
    }
}

__global__ __launch_bounds__(256) void scan3_kernel(const int* __restrict__ deg,
                                                    const int* __restrict__ bsum,
                                                    int* __restrict__ row_start) {
    __shared__ int sh[256];
    int t = threadIdx.x;
    int base = blockIdx.x * SCAN_CHUNK + t * 8;
    int v[8];
    int s = 0;
    #pragma unroll
    for (int j = 0; j < 8; ++j) {
        int idx = base + j;
        v[j] = (idx < NU) ? deg[idx] : 0;
        s += v[j];
    }
    sh[t] = s;
    __syncthreads();
    for (int off = 1; off < 256; off <<= 1) {
        int val = sh[t];
        int add = (t >= off) ? sh[t - off] : 0;
        __syncthreads();
        sh[t] = val + add;
        __syncthreads();
    }
    int excl = sh[t] - s + bsum[blockIdx.x];
    #pragma unroll
    for (int j = 0; j < 8; ++j) {
        int idx = base + j;
        if (idx < NU) row_start[idx] = excl;
        excl += v[j];
    }
}

// ---------- hist -> per-(r,k) cursor bases (thread-per-element, coalesced) -----
__global__ __launch_bounds__(256) void base_kernel(const int* __restrict__ row_start,
                                                   int* __restrict__ hist) {
    int d = blockIdx.x * 256 + threadIdx.x;
    if (d >= NU) return;
    int r = d / DRANGE, j = d - r * DRANGE;
    int* hb = hist + (size_t)r * K_CH * DRANGE + j;
    int acc = row_start[d];
    #pragma unroll
    for (int k = 0; k < K_CH; ++k) {
        int c = hb[(size_t)k * DRANGE];
        hb[(size_t)k * DRANGE] = acc;
        acc += c;
    }
}

// ---------- CSR fill: LDS cursors only, zero global atomics ----------
__global__ __launch_bounds__(256) void fill2(const int* __restrict__ src,
                                             const int* __restrict__ dst,
                                             const int* __restrict__ base,
                                             int* __restrict__ edge_src) {
    __shared__ int cur[DRANGE];  // 50 KB
    int r = blockIdx.x & (NXCD - 1);
    int k = blockIdx.x >> 3;
    int t = threadIdx.x;
    const int* bb = base + (size_t)(r * K_CH + k) * DRANGE;
    for (int j = t; j < DRANGE; j += 256) cur[j] = bb[j];
    __syncthreads();
    int lo = r * DRANGE;
    const int4* d4 = (const int4*)dst + (size_t)k * CHUNK4;
    const int4* s4 = (const int4*)src + (size_t)k * CHUNK4;
    for (int i = t; i < CHUNK4; i += 256) {
        int4 d = d4[i];
        int4 s = s4[i];
        if ((unsigned)(d.x - lo) < (unsigned)DRANGE) edge_src[atomicAdd(&cur[d.x - lo], 1)] = s.x;
        if ((unsigned)(d.y - lo) < (unsigned)DRANGE) edge_src[atomicAdd(&cur[d.y - lo], 1)] = s.y;
        if ((unsigned)(d.z - lo) < (unsigned)DRANGE) edge_src[atomicAdd(&cur[d.z - lo], 1)] = s.z;
        if ((unsigned)(d.w - lo) < (unsigned)DRANGE) edge_src[atomicAdd(&cur[d.w - lo], 1)] = s.w;
    }
}

// ---------- layer-1 aggregation: 4 edge-slots x 16 lanelets per wave ----------
__global__ __launch_bounds__(256) void agg_kernel(const unsigned* __restrict__ ubf,
                                                  const int* __restrict__ row_start,
                                                  const int* __restrict__ deg,
                                                  const int* __restrict__ edge_src,
                                                  unsigned* __restrict__ hn) {
    int wid = blockIdx.x * 4 + (threadIdx.x >> 6);
    int lane = threadIdx.x & 63;
    if (wid >= NU) return;
    int st = row_start[wid];
    int dg = deg[wid];
    int lanelet = lane & 15;
    int eslot = lane >> 4;
    float acc[8] = {0.f, 0.f, 0.f, 0.f, 0.f, 0.f, 0.f, 0.f};
    const unsigned* colp = ubf + (lanelet << 2);
    for (int base = 0; base < dg; base += 64) {
        int n = min(dg - base, 64);
        int myidx = (lane < n) ? edge_src[st + base + lane] : 0;
        int e = 0;
        #pragma unroll 2
        for (; e + 4 <= n; e += 4) {
            int s = __shfl(myidx, e + eslot, 64);
            u32x4 v = *(const u32x4*)(colp + (size_t)s * 64);
            #pragma unroll
            for (int k = 0; k < 4; ++k) {
                float2 f = unpack_bf16_pair(v[k]);
                acc[2 * k] += f.x;
                acc[2 * k + 1] += f.y;
            }
        }
        int rem = n - e;
        int s = __shfl(myidx, min(e + eslot, 63), 64);
        if (eslot < rem) {
            u32x4 v = *(const u32x4*)(colp + (size_t)s * 64);
            #pragma unroll
            for (int k = 0; k < 4; ++k) {
                float2 f = unpack_bf16_pair(v[k]);
                acc[2 * k] += f.x;
                acc[2 * k + 1] += f.y;
            }
        }
    }
    #pragma unroll
    for (int k = 0; k < 8; ++k) {
        acc[k] += __shfl_xor(acc[k], 16, 64);
        acc[k] += __shfl_xor(acc[k], 32, 64);
    }
    float inv = 1.0f / fmaxf((float)dg, 1.0f);
    if (eslot == 0) {
        u32x4 o;
        o[0] = pack_bf16_pair(acc[0] * inv, acc[1] * inv);
        o[1] = pack_bf16_pair(acc[2] * inv, acc[3] * inv);
        o[2] = pack_bf16_pair(acc[4] * inv, acc[5] * inv);
        o[3] = pack_bf16_pair(acc[6] * inv, acc[7] * inv);
        *(u32x4*)(hn + (size_t)wid * 64 + (lanelet << 2)) = o;
    }
}

// ---------- user layer 1 (all rows), MFMA ----------
__global__ __launch_bounds__(256) void user_mm_mfma(
    const float* __restrict__ hself, const unsigned short* __restrict__ hn,
    const u32x4* __restrict__ wf, const float* __restrict__ bias,
    float* __restrict__ out) {
    int t = threadIdx.x;
    int lane = t & 63;
    int tile = blockIdx.x * 4 + (t >> 6);
    if (tile >= USER_TILES) return;
    int gbase = tile * 16;
    int m = lane & 15, q = lane >> 4;
    const float* selfp = hself + (size_t)(gbase + m) * DD;
    const unsigned short* neighp = hn + (size_t)(gbase + m) * DD;
    bf16x8 as_hi[4], as_lo[4], an[4];
    #pragma unroll
    for (int kk = 0; kk < 4; ++kk) {
        int kb = kk * 32 + q * 8;
        make_afrag_hilo(selfp, kb, &as_hi[kk], &as_lo[kk]);
        frag_u f;
        f.u = *(const u32x4*)(neighp + kb);
        an[kk] = f.b;
    }
    f32x4 acc[8];
    f32x4 zero = {0.f, 0.f, 0.f, 0.f};
    #pragma unroll
    for (int j = 0; j < 8; ++j) acc[j] = zero;
    #pragma unroll 2
    for (int j = 0; j < 8; ++j) {
        #pragma unroll
        for (int kk = 0; kk < 4; ++kk) {
            bf16x8 bs = bfrag(wf, (j * 4 + kk) * 64 + lane);
            acc[j] = mfma16(as_hi[kk], bs, acc[j]);
            acc[j] = mfma16(as_lo[kk], bs, acc[j]);
            bf16x8 bn = bfrag(wf, 2048 + (j * 4 + kk) * 64 + lane);
            acc[j] = mfma16(an[kk], bn, acc[j]);
        }
    }
    float ss[4] = {0.f, 0.f, 0.f, 0.f};
    #pragma unroll
    for (int j = 0; j < 8; ++j) {
        float bj = bias[j * 16 + m];
        #pragma unroll
        for (int r = 0; r < 4; ++r) {
            float x = acc[j][r] + bj;
            x = x > 0.f ? x : 0.2f * x;
            acc[j][r] = x;
            ss[r] += x * x;
        }
    }
    #pragma unroll
    for (int r = 0; r < 4; ++r) {
        float s = ss[r];
        s += __shfl_xor(s, 1, 64);
        s += __shfl_xor(s, 2, 64);
        s += __shfl_xor(s, 4, 64);
        s += __shfl_xor(s, 8, 64);
        ss[r] = 1.0f / fmaxf(sqrtf(s), 1e-12f);
    }
    #pragma unroll
    for (int j = 0; j < 8; ++j)
        #pragma unroll
        for (int r = 0; r < 4; ++r)
            out[(size_t)(gbase + q * 4 + r) * DD + j * 16 + m] = acc[j][r] * ss[r];
}

// ---------- fused tail: user_l2 (blocks 0..1023) + item (blocks 1024..3071) ----
// One 16-row tile per BLOCK; the 8 j-columns split 2 per wave so all 4 waves run
// the MFMA phase. Row L2-norm crosses waves via ssp[] in LDS. LDS = 8.7 KB ->
// thread-capped 8 blocks/CU.
__global__ __launch_bounds__(256) void tail_fuse(
    const float* __restrict__ ufeat, const float* __restrict__ h1,
    const int* __restrict__ users, const int* __restrict__ row_start,
    const int* __restrict__ deg, const int* __restrict__ edge_src,
    const float* __restrict__ ifeat, const int* __restrict__ pos,
    const int* __restrict__ neg, const u32x4* __restrict__ wf_u,
    const u32x4* __restrict__ wf_i, const float* __restrict__ bu1,
    const float* __restrict__ bi0, const float* __restrict__ bi1,
    float* __restrict__ out) {
    __shared__ float sc[16 * 132];   // 8448 B tile scratch
    __shared__ float ssp[16 * 4];    // per-row per-wave partial sum-of-squares
    int t = threadIdx.x;
    int lane = t & 63, wave = t >> 6;
    int m = lane & 15, q = lane >> 4;
    f32x4 zero = {0.f, 0.f, 0.f, 0.f};

    if (blockIdx.x < 1024) {
        // ================= user layer 2 =================
        int gb = blockIdx.x * 16;
        int L = lane & 31;      // 16B lanelet of the row
        int eslot = lane >> 5;  // 2 concurrent edges
        const float* hl = h1 + 4 * L;
        #pragma unroll
        for (int rr = 0; rr < 4; ++rr) {
            int r = wave * 4 + rr;
            int u = users[gb + r];
            int st = row_start[u], dg = deg[u];
            float ax = 0.f, ay = 0.f, az = 0.f, aw = 0.f;
            for (int base = 0; base < dg; base += 64) {
                int n = min(dg - base, 64);
                int myidx = (lane < n) ? edge_src[st + base + lane] : 0;
                int e = 0;
                #pragma unroll 4
                for (; e + 2 <= n; e += 2) {
                    int s = __shfl(myidx, e + eslot, 64);
                    float4 v = *(const float4*)(hl + (size_t)s * DD);
                    ax += v.x; ay += v.y; az += v.z; aw += v.w;
                }
                if (e < n) {
                    int s = __shfl(myidx, e, 64);
                    if (eslot == 0) {
                        float4 v = *(const float4*)(hl + (size_t)s * DD);
                        ax += v.x; ay += v.y; az += v.z; aw += v.w;
                    }
                }
            }
            ax += __shfl_xor(ax, 32, 64);
            ay += __shfl_xor(ay, 32, 64);
            az += __shfl_xor(az, 32, 64);
            aw += __shfl_xor(aw, 32, 64);
            float inv = 1.0f / fmaxf((float)dg, 1.0f);
            if (eslot == 0) {
                float4 o = {ax * inv, ay * inv, az * inv, aw * inv};
                *(float4*)(sc + r * 132 + 4 * L) = o;
            }
            float* orow = out + (size_t)(gb + r) * 384;
            ((float2*)orow)[lane] = ((const float2*)(ufeat + (size_t)u * DD))[lane];
            ((float2*)orow)[64 + lane] = ((const float2*)(h1 + (size_t)u * DD))[lane];
        }
        __syncthreads();
        // phase 2: all 4 waves; wave w computes j = 2w, 2w+1
        int j0 = wave * 2;
        int um = users[gb + m];
        const float* selfp = h1 + (size_t)um * DD;
        bf16x8 sh[4], sl[4], nh[4], nl[4];
        #pragma unroll
        for (int kk = 0; kk < 4; ++kk) {
            int kb = kk * 32 + q * 8;
            make_afrag_hilo(selfp, kb, &sh[kk], &sl[kk]);
            make_afrag_hilo(sc + m * 132, kb, &nh[kk], &nl[kk]);
        }
        f32x4 a0 = zero, a1 = zero;
        #pragma unroll
        for (int kk = 0; kk < 4; ++kk) {
            bf16x8 b0 = bfrag(wf_u, (j0 * 4 + kk) * 64 + lane);
            a0 = mfma16(sh[kk], b0, a0);
            a0 = mfma16(sl[kk], b0, a0);
            bf16x8 n0 = bfrag(wf_u, 2048 + (j0 * 4 + kk) * 64 + lane);
            a0 = mfma16(nh[kk], n0, a0);
            a0 = mfma16(nl[kk], n0, a0);
            bf16x8 b1 = bfrag(wf_u, ((j0 + 1) * 4 + kk) * 64 + lane);
            a1 = mfma16(sh[kk], b1, a1);
            a1 = mfma16(sl[kk], b1, a1);
            bf16x8 n1 = bfrag(wf_u, 2048 + ((j0 + 1) * 4 + kk) * 64 + lane);
            a1 = mfma16(nh[kk], n1, a1);
            a1 = mfma16(nl[kk], n1, a1);
        }
        float bj0 = bu1[j0 * 16 + m], bj1 = bu1[(j0 + 1) * 16 + m];
        float ss[4];
        #pragma unroll
        for (int r = 0; r < 4; ++r) {
            float x0 = a0[r] + bj0; x0 = x0 > 0.f ? x0 : 0.2f * x0; a0[r] = x0;
            float x1 = a1[r] + bj1; x1 = x1 > 0.f ? x1 : 0.2f * x1; a1[r] = x1;
            float s = x0 * x0 + x1 * x1;
            s += __shfl_xor(s, 1, 64);
            s += __shfl_xor(s, 2, 64);
            s += __shfl_xor(s, 4, 64);
            s += __shfl_xor(s, 8, 64);
            ss[r] = s;
        }
        if (m == 0) {
            #pragma unroll
            for (int r = 0; r < 4; ++r) ssp[(q * 4 + r) * 4 + wave] = ss[r];
        }
        __syncthreads();
        #pragma unroll
        for (int r = 0; r < 4; ++r) {
            int row = q * 4 + r;
            float tot = ssp[row * 4] + ssp[row * 4 + 1] + ssp[row * 4 + 2] + ssp[row * 4 + 3];
            float inv = 1.0f / fmaxf(sqrtf(tot), 1e-12f);
            out[(size_t)(gb + row) * 384 + 256 + j0 * 16 + m] = a0[r] * inv;
            out[(size_t)(gb + row) * 384 + 256 + (j0 + 1) * 16 + m] = a1[r] * inv;
        }
        return;
    }

    // ================= item side: one tile per block, j split across waves =====
    int tile = blockIdx.x - 1024;  // 2048 tiles
    int gb = tile * 16;
    int j0 = wave * 2;
    int rowm = gb + m;
    int idxm = (rowm < BB) ? pos[rowm] : neg[rowm - BB];
    const float* rowp = ifeat + (size_t)idxm * DD;
    bf16x8 ahi[4], alo[4];
    #pragma unroll
    for (int kk = 0; kk < 4; ++kk)
        make_afrag_hilo(rowp, kk * 32 + q * 8, &ahi[kk], &alo[kk]);
    f32x4 a0 = zero, a1 = zero;
    #pragma unroll
    for (int kk = 0; kk < 4; ++kk) {
        bf16x8 b0 = bfrag(wf_i, (j0 * 4 + kk) * 64 + lane);
        a0 = mfma16(ahi[kk], b0, a0);
        a0 = mfma16(alo[kk], b0, a0);
        bf16x8 b1 = bfrag(wf_i, ((j0 + 1) * 4 + kk) * 64 + lane);
        a1 = mfma16(ahi[kk], b1, a1);
        a1 = mfma16(alo[kk], b1, a1);
    }
    // epilogue 0: cross-wave norm, write r1 to scratch
    {
        float bj0 = bi0[j0 * 16 + m], bj1 = bi0[(j0 + 1) * 16 + m];
        float ss[4];
        #pragma unroll
        for (int r = 0; r < 4; ++r) {
            float x0 = a0[r] + bj0; x0 = x0 > 0.f ? x0 : 0.2f * x0; a0[r] = x0;
            float x1 = a1[r] + bj1; x1 = x1 > 0.f ? x1 : 0.2f * x1; a1[r] = x1;
            float s = x0 * x0 + x1 * x1;
            s += __shfl_xor(s, 1, 64);
            s += __shfl_xor(s, 2, 64);
            s += __shfl_xor(s, 4, 64);
            s += __shfl_xor(s, 8, 64);
            ss[r] = s;
        }
        if (m == 0) {
            #pragma unroll
            for (int r = 0; r < 4; ++r) ssp[(q * 4 + r) * 4 + wave] = ss[r];
        }
        __syncthreads();
        #pragma unroll
        for (int r = 0; r < 4; ++r) {
            int row = q * 4 + r;
            float tot = ssp[row * 4] + ssp[row * 4 + 1] + ssp[row * 4 + 2] + ssp[row * 4 + 3];
            float inv = 1.0f / fmaxf(sqrtf(tot), 1e-12f);
            sc[row * 132 + j0 * 16 + m] = a0[r] * inv;
            sc[row * 132 + (j0 + 1) * 16 + m] = a1[r] * inv;
        }
        __syncthreads();
    }
    // copy r0 (raw gathered ifeat) and r1 (from scratch): rows split across waves
    #pragma unroll
    for (int rr = 0; rr < 4; ++rr) {
        int r = wave * 4 + rr;
        int row = gb + r;
        int idx = (row < BB) ? pos[row] : neg[row - BB];
        float* orow = out + (size_t)(BB + row) * 384;
        ((float2*)orow)[lane] = ((const float2*)(ifeat + (size_t)idx * DD))[lane];
        float2 r1v;
        r1v.x = sc[r * 132 + 2 * lane];
        r1v.y = sc[r * 132 + 2 * lane + 1];
        ((float2*)orow)[64 + lane] = r1v;
    }
    // layer 1: A-frags from scratch
    bf16x8 chi[4], clo[4];
    #pragma unroll
    for (int kk = 0; kk < 4; ++kk)
        make_afrag_hilo(sc + m * 132, kk * 32 + q * 8, &chi[kk], &clo[kk]);
    a0 = zero; a1 = zero;
    #pragma unroll
    for (int kk = 0; kk < 4; ++kk) {
        bf16x8 b0 = bfrag(wf_i, 2048 + (j0 * 4 + kk) * 64 + lane);
        a0 = mfma16(chi[kk], b0, a0);
        a0 = mfma16(clo[kk], b0, a0);
        bf16x8 b1 = bfrag(wf_i, 2048 + ((j0 + 1) * 4 + kk) * 64 + lane);
        a1 = mfma16(chi[kk], b1, a1);
        a1 = mfma16(clo[kk], b1, a1);
    }
    {
        float bj0 = bi1[j0 * 16 + m], bj1 = bi1[(j0 + 1) * 16 + m];
        float ss[4];
        #pragma unroll
        for (int r = 0; r < 4; ++r) {
            float x0 = a0[r] + bj0; x0 = x0 > 0.f ? x0 : 0.2f * x0; a0[r] = x0;
            float x1 = a1[r] + bj1; x1 = x1 > 0.f ? x1 : 0.2f * x1; a1[r] = x1;
            float s = x0 * x0 + x1 * x1;
            s += __shfl_xor(s, 1, 64);
            s += __shfl_xor(s, 2, 64);
            s += __shfl_xor(s, 4, 64);
            s += __shfl_xor(s, 8, 64);
            ss[r] = s;
        }
        __syncthreads();  // ensure prior ssp reads done before rewrite
        if (m == 0) {
            #pragma unroll
            for (int r = 0; r < 4; ++r) ssp[(q * 4 + r) * 4 + wave] = ss[r];
        }
        __syncthreads();
        #pragma unroll
        for (int r = 0; r < 4; ++r) {
            int row = q * 4 + r;
            float tot = ssp[row * 4] + ssp[row * 4 + 1] + ssp[row * 4 + 2] + ssp[row * 4 + 3];
            float inv = 1.0f / fmaxf(sqrtf(tot), 1e-12f);
            out[(size_t)(BB + gb + row) * 384 + 256 + j0 * 16 + m] = a0[r] * inv;
            out[(size_t)(BB + gb + row) * 384 + 256 + (j0 + 1) * 16 + m] = a1[r] * inv;
        }
    }
}

extern "C" void kernel_launch(void* const* d_in, const int* in_sizes, int n_in,
                              void* d_out, int out_size, void* d_ws, size_t ws_size,
                              hipStream_t stream) {
    const int* src = (const int*)d_in[0];
    const int* dst = (const int*)d_in[1];
    const int* users = (const int*)d_in[2];
    const int* pos = (const int*)d_in[3];
    const int* neg = (const int*)d_in[4];
    const float* ufeat = (const float*)d_in[5];
    const float* ifeat = (const float*)d_in[6];
    const float* Ws0 = (const float*)d_in[7];
    const float* Wn0 = (const float*)d_in[8];
    const float* bu0 = (const float*)d_in[9];
    const float* Wi0 = (const float*)d_in[10];
    const float* bi0 = (const float*)d_in[11];
    const float* Ws1 = (const float*)d_in[12];
    const float* Wn1 = (const float*)d_in[13];
    const float* bu1 = (const float*)d_in[14];
    const float* Wi1 = (const float*)d_in[15];
    const float* bi1 = (const float*)d_in[16];
    float* out = (float*)d_out;

    char* ws = (char*)d_ws;
    int* deg = (int*)(ws + OFF_DEG);
    int* row_start = (int*)(ws + OFF_ROWSTART);
    int* bsum = (int*)(ws + OFF_BSUM);
    int* edge_src = (int*)(ws + OFF_EDGESRC);
    float* h1 = (float*)(ws + OFF_H1);
    u32x4* wfrag = (u32x4*)(ws + OFF_WFRAG);

    unsigned* ubf = (unsigned*)d_out;                                    // bf16 ufeat
    unsigned* hn = (unsigned*)((char*)d_out + (size_t)NU * DD * 2);      // bf16 neighbor mean
    int* hist = (int*)((char*)d_out + (size_t)NU * DD * 4);              // 12.8MB at +51.2MB
    const unsigned short* hn_us = (const unsigned short*)hn;

    mega_prep<<<HIST_BLKS + PACK_BLKS + CVT_BLKS, 256, 0, stream>>>(
        dst, hist, ufeat, ubf, Ws0, Wn0, Ws1, Wn1, Wi0, Wi1, wfrag);
    scan1_kernel<<<SCAN_NBLK, 256, 0, stream>>>(hist, deg, bsum);
    scan2_kernel<<<1, 64, 0, stream>>>(bsum);
    scan3_kernel<<<SCAN_NBLK, 256, 0, stream>>>(deg, bsum, row_start);
    base_kernel<<<(NU + 255) / 256, 256, 0, stream>>>(row_start, hist);
    fill2<<<HIST_BLKS, 256, 0, stream>>>(src, dst, hist, edge_src);
    agg_kernel<<<(NU + 3) / 4, 256, 0, stream>>>(ubf, row_start, deg, edge_src, hn);
    user_mm_mfma<<<(USER_TILES + 3) / 4, 256, 0, stream>>>(ufeat, hn_us, wfrag, bu0, h1);
    tail_fuse<<<1024 + 2048, 256, 0, stream>>>(ufeat, h1, users, row_start, deg, edge_src,
                                               ifeat, pos, neg, wfrag + 4096, wfrag + 8192,
                                               bu1, bi0, bi1, out);
}

// Round 10
// 414.413 us; speedup vs baseline: 1.2140x; 1.0834x over previous
//
#include <hip/hip_runtime.h>

#define NU 100000
#define NI 100000
#define NE 1600000
#define BB 16384
#define DD 128

static constexpr int SCAN_CHUNK = 2048;                       // 256 threads * 8
static constexpr int SCAN_NBLK  = (NU + SCAN_CHUNK - 1) / SCAN_CHUNK; // 49
static constexpr int USER_TILES = NU / 16;                    // 6250

static constexpr int NXCD   = 8;
static constexpr int DRANGE = NU / NXCD;                      // 12500 dsts per range
static constexpr int K_CH   = 50;                             // edge chunks
static constexpr int CHUNK4 = NE / 4 / K_CH;                  // 8000 int4 per chunk
static constexpr int HIST_BLKS = NXCD * K_CH;                 // 400
static constexpr int PACK_BLKS = 48;
static constexpr int CVT_UNIT  = 2048;                        // uint2 outputs per block
static constexpr int CVT_TOT   = NU * 32;                     // 3.2M uint2 (= NU*64 uints)
static constexpr int CVT_BLKS  = (CVT_TOT + CVT_UNIT - 1) / CVT_UNIT; // 1563

// ---------- workspace layout (bytes) ----------
static constexpr size_t OFF_DEG      = 0;          // int[NU]   400000
static constexpr size_t OFF_ROWSTART = 400128;     // int[NU]
static constexpr size_t OFF_BSUM     = 1200384;    // int[64]
static constexpr size_t OFF_EDGESRC  = 1200640;    // int[NE]   6400000
static constexpr size_t OFF_H1       = 7600640;    // float[NU*DD] 51200000
static constexpr size_t OFF_WFRAG    = 58800640;   // u32x4[12288] 196608 (pre-swizzled bf16 weights)

// d_out staging (dead before real outputs are written):
//   ubf  at d_out+0          : uint[NU*64]   25.6 MB (ufeat bf16 pairs; dead after agg)
//   hn   at d_out+25.6MB     : ushort[NU*128] 25.6 MB (neighbor mean; dead after user_mm)
//   hist at d_out+51.2MB     : int[8*50*12500] 20 MB (chunk histograms / cursor bases;
//                              dead after fill2; 71.2MB < out_size 75.5MB)

typedef __bf16 bf16x8 __attribute__((ext_vector_type(8)));
typedef float f32x4 __attribute__((ext_vector_type(4)));
typedef unsigned int u32x4 __attribute__((ext_vector_type(4)));

union frag_u {
    u32x4 u;
    bf16x8 b;
    unsigned short us[8];
};

// ---------- helpers ----------
__device__ __forceinline__ unsigned short f2bf(float f) {
    unsigned u = __float_as_uint(f);
    u = (u + 0x7fffu + ((u >> 16) & 1u)) >> 16;  // RNE
    return (unsigned short)u;
}

__device__ __forceinline__ unsigned pack_bf16_pair(float a, float b) {
    return (unsigned)f2bf(a) | ((unsigned)f2bf(b) << 16);
}

__device__ __forceinline__ float2 unpack_bf16_pair(unsigned u) {
    float2 r;
    r.x = __uint_as_float(u << 16);
    r.y = __uint_as_float(u & 0xffff0000u);
    return r;
}

__device__ __forceinline__ f32x4 mfma16(bf16x8 a, bf16x8 b, f32x4 c) {
    return __builtin_amdgcn_mfma_f32_16x16x32_bf16(a, b, c, 0, 0, 0);
}

__device__ __forceinline__ bf16x8 bfrag(const u32x4* __restrict__ wf, int idx) {
    frag_u f;
    f.u = wf[idx];
    return f.b;
}

// A-fragment (16x16x32 layout: lane holds A[m=lane&15][kb..kb+7]) as hi/lo bf16 split.
__device__ __forceinline__ void make_afrag_hilo(const float* rowp, int kb,
                                                bf16x8* hi, bf16x8* lo) {
    float4 v0 = *(const float4*)(rowp + kb);
    float4 v1 = *(const float4*)(rowp + kb + 4);
    float vv[8] = {v0.x, v0.y, v0.z, v0.w, v1.x, v1.y, v1.z, v1.w};
    frag_u h, l;
    #pragma unroll
    for (int e = 0; e < 8; ++e) {
        unsigned short hb = f2bf(vv[e]);
        h.us[e] = hb;
        float hf = __uint_as_float(((unsigned)hb) << 16);
        l.us[e] = f2bf(vv[e] - hf);
    }
    *hi = h.b;
    *lo = l.b;
}

// ---------- hist: private LDS histograms, 512 threads, 400 blocks ----------
// Block (k,r): histogram of chunk k filtered to dst-range r; plain coalesced
// flush -> hist[r][k][*]. Zero global atomics. 8 waves/block for LDS-atomic
// and load parallelism (was 4 waves at 256 threads, 1 blk/CU).
__global__ __launch_bounds__(512) void hist_kernel(const int* __restrict__ dst,
                                                   int* __restrict__ hist) {
    __shared__ int h[DRANGE];  // 50 KB
    int t = threadIdx.x;
    int r = blockIdx.x & (NXCD - 1);
    int k = blockIdx.x >> 3;
    for (int j = t; j < DRANGE; j += 512) h[j] = 0;
    __syncthreads();
    int lo = r * DRANGE;
    const int4* d4 = (const int4*)dst + (size_t)k * CHUNK4;
    for (int i = t; i < CHUNK4; i += 512) {
        int4 d = d4[i];
        if ((unsigned)(d.x - lo) < (unsigned)DRANGE) atomicAdd(&h[d.x - lo], 1);
        if ((unsigned)(d.y - lo) < (unsigned)DRANGE) atomicAdd(&h[d.y - lo], 1);
        if ((unsigned)(d.z - lo) < (unsigned)DRANGE) atomicAdd(&h[d.z - lo], 1);
        if ((unsigned)(d.w - lo) < (unsigned)DRANGE) atomicAdd(&h[d.w - lo], 1);
    }
    __syncthreads();
    int* hb = hist + (size_t)(r * K_CH + k) * DRANGE;
    for (int j = t; j < DRANGE; j += 512) hb[j] = h[j];
}

// ---------- pack + cvt: LDS-free (full occupancy, unthrottled streaming) ------
__global__ __launch_bounds__(256) void pack_cvt_kernel(
    const float* __restrict__ uf, unsigned* __restrict__ ubf,
    const float* __restrict__ Ws0, const float* __restrict__ Wn0,
    const float* __restrict__ Ws1, const float* __restrict__ Wn1,
    const float* __restrict__ Wi0, const float* __restrict__ Wi1,
    u32x4* __restrict__ wfrag) {
    int t = threadIdx.x;
    if (blockIdx.x < PACK_BLKS) {
        int i = blockIdx.x * 256 + t;  // 12288 exact
        const float* tab[6] = {Ws0, Wn0, Ws1, Wn1, Wi0, Wi1};
        int matg = i >> 11;
        int j = (i >> 8) & 7, kk = (i >> 6) & 3, ln = i & 63;
        const float* W = tab[matg];
        int n = j * 16 + (ln & 15);
        int kb = kk * 32 + (ln >> 4) * 8;
        unsigned short u[8];
        #pragma unroll
        for (int e = 0; e < 8; ++e) u[e] = f2bf(W[(size_t)(kb + e) * DD + n]);
        u32x4 w;
        w[0] = u[0] | ((unsigned)u[1] << 16);
        w[1] = u[2] | ((unsigned)u[3] << 16);
        w[2] = u[4] | ((unsigned)u[5] << 16);
        w[3] = u[6] | ((unsigned)u[7] << 16);
        wfrag[i] = w;
    } else {
        int bid2 = blockIdx.x - PACK_BLKS;
        const float4* uf4 = (const float4*)uf;
        uint2* ub2 = (uint2*)ubf;
        #pragma unroll
        for (int it = 0; it < 8; ++it) {
            int idx = bid2 * CVT_UNIT + it * 256 + t;
            if (idx < CVT_TOT) {
                float4 v = uf4[idx];
                uint2 o;
                o.x = pack_bf16_pair(v.x, v.y);
                o.y = pack_bf16_pair(v.z, v.w);
                ub2[idx] = o;
            }
        }
    }
}

// ---------- deg[d] = sum_k hist[r][k][j] (thread-per-element, coalesced) -------
__global__ __launch_bounds__(256) void deg_reduce(const int* __restrict__ hist,
                                                  int* __restrict__ deg) {
    int d = blockIdx.x * 256 + threadIdx.x;
    if (d >= NU) return;
    int r = d / DRANGE, j = d - r * DRANGE;
    const int* hb = hist + (size_t)r * K_CH * DRANGE + j;
    int s = 0;
    for (int k = 0; k < K_CH; ++k) s += hb[(size_t)k * DRANGE];
    deg[d] = s;
}

__global__ __launch_bounds__(256) void scan1_kernel(const int* __restrict__ deg,
                                                    int* __restrict__ bsum) {
    __shared__ int sh[256];
    int t = threadIdx.x;
    int base = blockIdx.x * SCAN_CHUNK + t * 8;
    int s = 0;
    #pragma unroll
    for (int j = 0; j < 8; ++j) {
        int idx = base + j;
        s += (idx < NU) ? deg[idx] : 0;
    }
    sh[t] = s;
    __syncthreads();
    for (int off = 128; off > 0; off >>= 1) {
        if (t < off) sh[t] += sh[t + off];
        __syncthreads();
    }
    if (t == 0) bsum[blockIdx.x] = sh[0];
}

__global__ void scan2_kernel(int* __restrict__ bsum) {
    if (threadIdx.x == 0) {
        int acc = 0;
        for (int i = 0; i < SCAN_NBLK; ++i) {
            int v = bsum[i];
            bsum[i] = acc;
            acc += v;
        }
    }
}

__global__ __launch_bounds__(256) void scan3_kernel(const int* __restrict__ deg,
                                                    const int* __restrict__ bsum,
                                                    int* __restrict__ row_start) {
    __shared__ int sh[256];
    int t = threadIdx.x;
    int base = blockIdx.x * SCAN_CHUNK + t * 8;
    int v[8];
    int s = 0;
    #pragma unroll
    for (int j = 0; j < 8; ++j) {
        int idx = base + j;
        v[j] = (idx < NU) ? deg[idx] : 0;
        s += v[j];
    }
    sh[t] = s;
    __syncthreads();
    for (int off = 1; off < 256; off <<= 1) {
        int val = sh[t];
        int add = (t >= off) ? sh[t - off] : 0;
        __syncthreads();
        sh[t] = val + add;
        __syncthreads();
    }
    int excl = sh[t] - s + bsum[blockIdx.x];
    #pragma unroll
    for (int j = 0; j < 8; ++j) {
        int idx = base + j;
        if (idx < NU) row_start[idx] = excl;
        excl += v[j];
    }
}

// ---------- hist -> per-(r,k) cursor bases (thread-per-element, coalesced) -----
__global__ __launch_bounds__(256) void base_kernel(const int* __restrict__ row_start,
                                                   int* __restrict__ hist) {
    int d = blockIdx.x * 256 + threadIdx.x;
    if (d >= NU) return;
    int r = d / DRANGE, j = d - r * DRANGE;
    int* hb = hist + (size_t)r * K_CH * DRANGE + j;
    int acc = row_start[d];
    for (int k = 0; k < K_CH; ++k) {
        int c = hb[(size_t)k * DRANGE];
        hb[(size_t)k * DRANGE] = acc;
        acc += c;
    }
}

// ---------- CSR fill: LDS cursors only, 512 threads, 400 blocks ----------
__global__ __launch_bounds__(512) void fill2(const int* __restrict__ src,
                                             const int* __restrict__ dst,
                                             const int* __restrict__ base,
                                             int* __restrict__ edge_src) {
    __shared__ int cur[DRANGE];  // 50 KB
    int r = blockIdx.x & (NXCD - 1);
    int k = blockIdx.x >> 3;
    int t = threadIdx.x;
    const int* bb = base + (size_t)(r * K_CH + k) * DRANGE;
    for (int j = t; j < DRANGE; j += 512) cur[j] = bb[j];
    __syncthreads();
    int lo = r * DRANGE;
    const int4* d4 = (const int4*)dst + (size_t)k * CHUNK4;
    const int4* s4 = (const int4*)src + (size_t)k * CHUNK4;
    for (int i = t; i < CHUNK4; i += 512) {
        int4 d = d4[i];
        int4 s = s4[i];
        if ((unsigned)(d.x - lo) < (unsigned)DRANGE) edge_src[atomicAdd(&cur[d.x - lo], 1)] = s.x;
        if ((unsigned)(d.y - lo) < (unsigned)DRANGE) edge_src[atomicAdd(&cur[d.y - lo], 1)] = s.y;
        if ((unsigned)(d.z - lo) < (unsigned)DRANGE) edge_src[atomicAdd(&cur[d.z - lo], 1)] = s.z;
        if ((unsigned)(d.w - lo) < (unsigned)DRANGE) edge_src[atomicAdd(&cur[d.w - lo], 1)] = s.w;
    }
}

// ---------- layer-1 aggregation: 4 edge-slots x 16 lanelets per wave ----------
__global__ __launch_bounds__(256) void agg_kernel(const unsigned* __restrict__ ubf,
                                                  const int* __restrict__ row_start,
                                                  const int* __restrict__ deg,
                                                  const int* __restrict__ edge_src,
                                                  unsigned* __restrict__ hn) {
    int wid = blockIdx.x * 4 + (threadIdx.x >> 6);
    int lane = threadIdx.x & 63;
    if (wid >= NU) return;
    int st = row_start[wid];
    int dg = deg[wid];
    int lanelet = lane & 15;
    int eslot = lane >> 4;
    float acc[8] = {0.f, 0.f, 0.f, 0.f, 0.f, 0.f, 0.f, 0.f};
    const unsigned* colp = ubf + (lanelet << 2);
    for (int base = 0; base < dg; base += 64) {
        int n = min(dg - base, 64);
        int myidx = (lane < n) ? edge_src[st + base + lane] : 0;
        int e = 0;
        #pragma unroll 2
        for (; e + 4 <= n; e += 4) {
            int s = __shfl(myidx, e + eslot, 64);
            u32x4 v = *(const u32x4*)(colp + (size_t)s * 64);
            #pragma unroll
            for (int k = 0; k < 4; ++k) {
                float2 f = unpack_bf16_pair(v[k]);
                acc[2 * k] += f.x;
                acc[2 * k + 1] += f.y;
            }
        }
        int rem = n - e;
        int s = __shfl(myidx, min(e + eslot, 63), 64);
        if (eslot < rem) {
            u32x4 v = *(const u32x4*)(colp + (size_t)s * 64);
            #pragma unroll
            for (int k = 0; k < 4; ++k) {
                float2 f = unpack_bf16_pair(v[k]);
                acc[2 * k] += f.x;
                acc[2 * k + 1] += f.y;
            }
        }
    }
    #pragma unroll
    for (int k = 0; k < 8; ++k) {
        acc[k] += __shfl_xor(acc[k], 16, 64);
        acc[k] += __shfl_xor(acc[k], 32, 64);
    }
    float inv = 1.0f / fmaxf((float)dg, 1.0f);
    if (eslot == 0) {
        u32x4 o;
        o[0] = pack_bf16_pair(acc[0] * inv, acc[1] * inv);
        o[1] = pack_bf16_pair(acc[2] * inv, acc[3] * inv);
        o[2] = pack_bf16_pair(acc[4] * inv, acc[5] * inv);
        o[3] = pack_bf16_pair(acc[6] * inv, acc[7] * inv);
        *(u32x4*)(hn + (size_t)wid * 64 + (lanelet << 2)) = o;
    }
}

// ---------- user layer 1 (all rows), MFMA ----------
__global__ __launch_bounds__(256) void user_mm_mfma(
    const float* __restrict__ hself, const unsigned short* __restrict__ hn,
    const u32x4* __restrict__ wf, const float* __restrict__ bias,
    float* __restrict__ out) {
    int t = threadIdx.x;
    int lane = t & 63;
    int tile = blockIdx.x * 4 + (t >> 6);
    if (tile >= USER_TILES) return;
    int gbase = tile * 16;
    int m = lane & 15, q = lane >> 4;
    const float* selfp = hself + (size_t)(gbase + m) * DD;
    const unsigned short* neighp = hn + (size_t)(gbase + m) * DD;
    bf16x8 as_hi[4], as_lo[4], an[4];
    #pragma unroll
    for (int kk = 0; kk < 4; ++kk) {
        int kb = kk * 32 + q * 8;
        make_afrag_hilo(selfp, kb, &as_hi[kk], &as_lo[kk]);
        frag_u f;
        f.u = *(const u32x4*)(neighp + kb);
        an[kk] = f.b;
    }
    f32x4 acc[8];
    f32x4 zero = {0.f, 0.f, 0.f, 0.f};
    #pragma unroll
    for (int j = 0; j < 8; ++j) acc[j] = zero;
    #pragma unroll 2
    for (int j = 0; j < 8; ++j) {
        #pragma unroll
        for (int kk = 0; kk < 4; ++kk) {
            bf16x8 bs = bfrag(wf, (j * 4 + kk) * 64 + lane);
            acc[j] = mfma16(as_hi[kk], bs, acc[j]);
            acc[j] = mfma16(as_lo[kk], bs, acc[j]);
            bf16x8 bn = bfrag(wf, 2048 + (j * 4 + kk) * 64 + lane);
            acc[j] = mfma16(an[kk], bn, acc[j]);
        }
    }
    float ss[4] = {0.f, 0.f, 0.f, 0.f};
    #pragma unroll
    for (int j = 0; j < 8; ++j) {
        float bj = bias[j * 16 + m];
        #pragma unroll
        for (int r = 0; r < 4; ++r) {
            float x = acc[j][r] + bj;
            x = x > 0.f ? x : 0.2f * x;
            acc[j][r] = x;
            ss[r] += x * x;
        }
    }
    #pragma unroll
    for (int r = 0; r < 4; ++r) {
        float s = ss[r];
        s += __shfl_xor(s, 1, 64);
        s += __shfl_xor(s, 2, 64);
        s += __shfl_xor(s, 4, 64);
        s += __shfl_xor(s, 8, 64);
        ss[r] = 1.0f / fmaxf(sqrtf(s), 1e-12f);
    }
    #pragma unroll
    for (int j = 0; j < 8; ++j)
        #pragma unroll
        for (int r = 0; r < 4; ++r)
            out[(size_t)(gbase + q * 4 + r) * DD + j * 16 + m] = acc[j][r] * ss[r];
}

// ---------- fused tail: user_l2 (blocks 0..1023) + item (blocks 1024..3071) ----
__global__ __launch_bounds__(256) void tail_fuse(
    const float* __restrict__ ufeat, const float* __restrict__ h1,
    const int* __restrict__ users, const int* __restrict__ row_start,
    const int* __restrict__ deg, const int* __restrict__ edge_src,
    const float* __restrict__ ifeat, const int* __restrict__ pos,
    const int* __restrict__ neg, const u32x4* __restrict__ wf_u,
    const u32x4* __restrict__ wf_i, const float* __restrict__ bu1,
    const float* __restrict__ bi0, const float* __restrict__ bi1,
    float* __restrict__ out) {
    __shared__ float sc[16 * 132];   // 8448 B tile scratch
    __shared__ float ssp[16 * 4];    // per-row per-wave partial sum-of-squares
    int t = threadIdx.x;
    int lane = t & 63, wave = t >> 6;
    int m = lane & 15, q = lane >> 4;
    f32x4 zero = {0.f, 0.f, 0.f, 0.f};

    if (blockIdx.x < 1024) {
        // ================= user layer 2 =================
        int gb = blockIdx.x * 16;
        int L = lane & 31;      // 16B lanelet of the row
        int eslot = lane >> 5;  // 2 concurrent edges
        const float* hl = h1 + 4 * L;
        #pragma unroll
        for (int rr = 0; rr < 4; ++rr) {
            int r = wave * 4 + rr;
            int u = users[gb + r];
            int st = row_start[u], dg = deg[u];
            float ax = 0.f, ay = 0.f, az = 0.f, aw = 0.f;
            for (int base = 0; base < dg; base += 64) {
                int n = min(dg - base, 64);
                int myidx = (lane < n) ? edge_src[st + base + lane] : 0;
                int e = 0;
                #pragma unroll 4
                for (; e + 2 <= n; e += 2) {
                    int s = __shfl(myidx, e + eslot, 64);
                    float4 v = *(const float4*)(hl + (size_t)s * DD);
                    ax += v.x; ay += v.y; az += v.z; aw += v.w;
                }
                if (e < n) {
                    int s = __shfl(myidx, e, 64);
                    if (eslot == 0) {
                        float4 v = *(const float4*)(hl + (size_t)s * DD);
                        ax += v.x; ay += v.y; az += v.z; aw += v.w;
                    }
                }
            }
            ax += __shfl_xor(ax, 32, 64);
            ay += __shfl_xor(ay, 32, 64);
            az += __shfl_xor(az, 32, 64);
            aw += __shfl_xor(aw, 32, 64);
            float inv = 1.0f / fmaxf((float)dg, 1.0f);
            if (eslot == 0) {
                float4 o = {ax * inv, ay * inv, az * inv, aw * inv};
                *(float4*)(sc + r * 132 + 4 * L) = o;
            }
            float* orow = out + (size_t)(gb + r) * 384;
            ((float2*)orow)[lane] = ((const float2*)(ufeat + (size_t)u * DD))[lane];
            ((float2*)orow)[64 + lane] = ((const float2*)(h1 + (size_t)u * DD))[lane];
        }
        __syncthreads();
        // phase 2: all 4 waves; wave w computes j = 2w, 2w+1
        int j0 = wave * 2;
        int um = users[gb + m];
        const float* selfp = h1 + (size_t)um * DD;
        bf16x8 sh[4], sl[4], nh[4], nl[4];
        #pragma unroll
        for (int kk = 0; kk < 4; ++kk) {
            int kb = kk * 32 + q * 8;
            make_afrag_hilo(selfp, kb, &sh[kk], &sl[kk]);
            make_afrag_hilo(sc + m * 132, kb, &nh[kk], &nl[kk]);
        }
        f32x4 a0 = zero, a1 = zero;
        #pragma unroll
        for (int kk = 0; kk < 4; ++kk) {
            bf16x8 b0 = bfrag(wf_u, (j0 * 4 + kk) * 64 + lane);
            a0 = mfma16(sh[kk], b0, a0);
            a0 = mfma16(sl[kk], b0, a0);
            bf16x8 n0 = bfrag(wf_u, 2048 + (j0 * 4 + kk) * 64 + lane);
            a0 = mfma16(nh[kk], n0, a0);
            a0 = mfma16(nl[kk], n0, a0);
            bf16x8 b1 = bfrag(wf_u, ((j0 + 1) * 4 + kk) * 64 + lane);
            a1 = mfma16(sh[kk], b1, a1);
            a1 = mfma16(sl[kk], b1, a1);
            bf16x8 n1 = bfrag(wf_u, 2048 + ((j0 + 1) * 4 + kk) * 64 + lane);
            a1 = mfma16(nh[kk], n1, a1);
            a1 = mfma16(nl[kk], n1, a1);
        }
        float bj0 = bu1[j0 * 16 + m], bj1 = bu1[(j0 + 1) * 16 + m];
        float ss[4];
        #pragma unroll
        for (int r = 0; r < 4; ++r) {
            float x0 = a0[r] + bj0; x0 = x0 > 0.f ? x0 : 0.2f * x0; a0[r] = x0;
            float x1 = a1[r] + bj1; x1 = x1 > 0.f ? x1 : 0.2f * x1; a1[r] = x1;
            float s = x0 * x0 + x1 * x1;
            s += __shfl_xor(s, 1, 64);
            s += __shfl_xor(s, 2, 64);
            s += __shfl_xor(s, 4, 64);
            s += __shfl_xor(s, 8, 64);
            ss[r] = s;
        }
        if (m == 0) {
            #pragma unroll
            for (int r = 0; r < 4; ++r) ssp[(q * 4 + r) * 4 + wave] = ss[r];
        }
        __syncthreads();
        #pragma unroll
        for (int r = 0; r < 4; ++r) {
            int row = q * 4 + r;
            float tot = ssp[row * 4] + ssp[row * 4 + 1] + ssp[row * 4 + 2] + ssp[row * 4 + 3];
            float inv = 1.0f / fmaxf(sqrtf(tot), 1e-12f);
            out[(size_t)(gb + row) * 384 + 256 + j0 * 16 + m] = a0[r] * inv;
            out[(size_t)(gb + row) * 384 + 256 + (j0 + 1) * 16 + m] = a1[r] * inv;
        }
        return;
    }

    // ================= item side: one tile per block, j split across waves =====
    int tile = blockIdx.x - 1024;  // 2048 tiles
    int gb = tile * 16;
    int j0 = wave * 2;
    int rowm = gb + m;
    int idxm = (rowm < BB) ? pos[rowm] : neg[rowm - BB];
    const float* rowp = ifeat + (size_t)idxm * DD;
    bf16x8 ahi[4], alo[4];
    #pragma unroll
    for (int kk = 0; kk < 4; ++kk)
        make_afrag_hilo(rowp, kk * 32 + q * 8, &ahi[kk], &alo[kk]);
    f32x4 a0 = zero, a1 = zero;
    #pragma unroll
    for (int kk = 0; kk < 4; ++kk) {
        bf16x8 b0 = bfrag(wf_i, (j0 * 4 + kk) * 64 + lane);
        a0 = mfma16(ahi[kk], b0, a0);
        a0 = mfma16(alo[kk], b0, a0);
        bf16x8 b1 = bfrag(wf_i, ((j0 + 1) * 4 + kk) * 64 + lane);
        a1 = mfma16(ahi[kk], b1, a1);
        a1 = mfma16(alo[kk], b1, a1);
    }
    // epilogue 0: cross-wave norm, write r1 to scratch
    {
        float bj0 = bi0[j0 * 16 + m], bj1 = bi0[(j0 + 1) * 16 + m];
        float ss[4];
        #pragma unroll
        for (int r = 0; r < 4; ++r) {
            float x0 = a0[r] + bj0; x0 = x0 > 0.f ? x0 : 0.2f * x0; a0[r] = x0;
            float x1 = a1[r] + bj1; x1 = x1 > 0.f ? x1 : 0.2f * x1; a1[r] = x1;
            float s = x0 * x0 + x1 * x1;
            s += __shfl_xor(s, 1, 64);
            s += __shfl_xor(s, 2, 64);
            s += __shfl_xor(s, 4, 64);
            s += __shfl_xor(s, 8, 64);
            ss[r] = s;
        }
        if (m == 0) {
            #pragma unroll
            for (int r = 0; r < 4; ++r) ssp[(q * 4 + r) * 4 + wave] = ss[r];
        }
        __syncthreads();
        #pragma unroll
        for (int r = 0; r < 4; ++r) {
            int row = q * 4 + r;
            float tot = ssp[row * 4] + ssp[row * 4 + 1] + ssp[row * 4 + 2] + ssp[row * 4 + 3];
            float inv = 1.0f / fmaxf(sqrtf(tot), 1e-12f);
            sc[row * 132 + j0 * 16 + m] = a0[r] * inv;
            sc[row * 132 + (j0 + 1) * 16 + m] = a1[r] * inv;
        }
        __syncthreads();
    }
    // copy r0 (raw gathered ifeat) and r1 (from scratch): rows split across waves
    #pragma unroll
    for (int rr = 0; rr < 4; ++rr) {
        int r = wave * 4 + rr;
        int row = gb + r;
        int idx = (row < BB) ? pos[row] : neg[row - BB];
        float* orow = out + (size_t)(BB + row) * 384;
        ((float2*)orow)[lane] = ((const float2*)(ifeat + (size_t)idx * DD))[lane];
        float2 r1v;
        r1v.x = sc[r * 132 + 2 * lane];
        r1v.y = sc[r * 132 + 2 * lane + 1];
        ((float2*)orow)[64 + lane] = r1v;
    }
    // layer 1: A-frags from scratch
    bf16x8 chi[4], clo[4];
    #pragma unroll
    for (int kk = 0; kk < 4; ++kk)
        make_afrag_hilo(sc + m * 132, kk * 32 + q * 8, &chi[kk], &clo[kk]);
    a0 = zero; a1 = zero;
    #pragma unroll
    for (int kk = 0; kk < 4; ++kk) {
        bf16x8 b0 = bfrag(wf_i, 2048 + (j0 * 4 + kk) * 64 + lane);
        a0 = mfma16(chi[kk], b0, a0);
        a0 = mfma16(clo[kk], b0, a0);
        bf16x8 b1 = bfrag(wf_i, 2048 + ((j0 + 1) * 4 + kk) * 64 + lane);
        a1 = mfma16(chi[kk], b1, a1);
        a1 = mfma16(clo[kk], b1, a1);
    }
    {
        float bj0 = bi1[j0 * 16 + m], bj1 = bi1[(j0 + 1) * 16 + m];
        float ss[4];
        #pragma unroll
        for (int r = 0; r < 4; ++r) {
            float x0 = a0[r] + bj0; x0 = x0 > 0.f ? x0 : 0.2f * x0; a0[r] = x0;
            float x1 = a1[r] + bj1; x1 = x1 > 0.f ? x1 : 0.2f * x1; a1[r] = x1;
            float s = x0 * x0 + x1 * x1;
            s += __shfl_xor(s, 1, 64);
            s += __shfl_xor(s, 2, 64);
            s += __shfl_xor(s, 4, 64);
            s += __shfl_xor(s, 8, 64);
            ss[r] = s;
        }
        __syncthreads();  // ensure prior ssp reads done before rewrite
        if (m == 0) {
            #pragma unroll
            for (int r = 0; r < 4; ++r) ssp[(q * 4 + r) * 4 + wave] = ss[r];
        }
        __syncthreads();
        #pragma unroll
        for (int r = 0; r < 4; ++r) {
            int row = q * 4 + r;
            float tot = ssp[row * 4] + ssp[row * 4 + 1] + ssp[row * 4 + 2] + ssp[row * 4 + 3];
            float inv = 1.0f / fmaxf(sqrtf(tot), 1e-12f);
            out[(size_t)(BB + gb + row) * 384 + 256 + j0 * 16 + m] = a0[r] * inv;
            out[(size_t)(BB + gb + row) * 384 + 256 + (j0 + 1) * 16 + m] = a1[r] * inv;
        }
    }
}

extern "C" void kernel_launch(void* const* d_in, const int* in_sizes, int n_in,
                              void* d_out, int out_size, void* d_ws, size_t ws_size,
                              hipStream_t stream) {
    const int* src = (const int*)d_in[0];
    const int* dst = (const int*)d_in[1];
    const int* users = (const int*)d_in[2];
    const int* pos = (const int*)d_in[3];
    const int* neg = (const int*)d_in[4];
    const float* ufeat = (const float*)d_in[5];
    const float* ifeat = (const float*)d_in[6];
    const float* Ws0 = (const float*)d_in[7];
    const float* Wn0 = (const float*)d_in[8];
    const float* bu0 = (const float*)d_in[9];
    const float* Wi0 = (const float*)d_in[10];
    const float* bi0 = (const float*)d_in[11];
    const float* Ws1 = (const float*)d_in[12];
    const float* Wn1 = (const float*)d_in[13];
    const float* bu1 = (const float*)d_in[14];
    const float* Wi1 = (const float*)d_in[15];
    const float* bi1 = (const float*)d_in[16];
    float* out = (float*)d_out;

    char* ws = (char*)d_ws;
    int* deg = (int*)(ws + OFF_DEG);
    int* row_start = (int*)(ws + OFF_ROWSTART);
    int* bsum = (int*)(ws + OFF_BSUM);
    int* edge_src = (int*)(ws + OFF_EDGESRC);
    float* h1 = (float*)(ws + OFF_H1);
    u32x4* wfrag = (u32x4*)(ws + OFF_WFRAG);

    unsigned* ubf = (unsigned*)d_out;                                    // bf16 ufeat
    unsigned* hn = (unsigned*)((char*)d_out + (size_t)NU * DD * 2);      // bf16 neighbor mean
    int* hist = (int*)((char*)d_out + (size_t)NU * DD * 4);              // 20MB at +51.2MB
    const unsigned short* hn_us = (const unsigned short*)hn;

    hist_kernel<<<HIST_BLKS, 512, 0, stream>>>(dst, hist);
    pack_cvt_kernel<<<PACK_BLKS + CVT_BLKS, 256, 0, stream>>>(
        ufeat, ubf, Ws0, Wn0, Ws1, Wn1, Wi0, Wi1, wfrag);
    deg_reduce<<<(NU + 255) / 256, 256, 0, stream>>>(hist, deg);
    scan1_kernel<<<SCAN_NBLK, 256, 0, stream>>>(deg, bsum);
    scan2_kernel<<<1, 64, 0, stream>>>(bsum);
    scan3_kernel<<<SCAN_NBLK, 256, 0, stream>>>(deg, bsum, row_start);
    base_kernel<<<(NU + 255) / 256, 256, 0, stream>>>(row_start, hist);
    fill2<<<HIST_BLKS, 512, 0, stream>>>(src, dst, hist, edge_src);
    agg_kernel<<<(NU + 3) / 4, 256, 0, stream>>>(ubf, row_start, deg, edge_src, hn);
    user_mm_mfma<<<(USER_TILES + 3) / 4, 256, 0, stream>>>(ufeat, hn_us, wfrag, bu0, h1);
    tail_fuse<<<1024 + 2048, 256, 0, stream>>>(ufeat, h1, users, row_start, deg, edge_src,
                                               ifeat, pos, neg, wfrag + 4096, wfrag + 8192,
                                               bu1, bi0, bi1, out);
}